// Round 2
// baseline (2088.625 us; speedup 1.0000x reference)
//
#include <hip/hip_runtime.h>
#include <math.h>

// Gated Slot Attention forward, MI355X round 1.
// B=2, T=2048, D=1024, H=4, DK=DV=M=256. Row width H*256 = 1024 everywhere.
// Inputs detected at runtime as bf16 (harness-converted) or fp32; all compute fp32.
// Workspace budget: 256 B + 5 * 16 MB = 80 MB (R0 used 132 MB -> OOB -> corrupted
// pristine inputs -> post-timing divergence).
#define TLEN 2048
#define NROWS 4096   // B*T

// ---------------- dtype helpers ----------------
__device__ __forceinline__ float bf2f(unsigned short u) {
    unsigned v = ((unsigned)u) << 16; float f; __builtin_memcpy(&f, &v, 4); return f;
}
__device__ __forceinline__ unsigned short f2bf(float x) {
    unsigned u; __builtin_memcpy(&u, &x, 4);
    u += 0x7FFFu + ((u >> 16) & 1u);            // round-to-nearest-even
    return (unsigned short)(u >> 16);
}
__device__ __forceinline__ float siluf(float x) { return x / (1.f + expf(-x)); }

// g_w is exactly ones(1024): first 32-bit word distinguishes fp32 (0x3F800000)
// from packed bf16 (0x3F803F80). Deterministic, recomputed every call.
__global__ void gsa_detect(const unsigned* __restrict__ gw, int* __restrict__ flag) {
    *flag = (gw[0] == 0x3F803F80u) ? 1 : 0;
}

__global__ __launch_bounds__(256) void gsa_emit(const float* __restrict__ src,
        void* __restrict__ dst, int n4, const int* __restrict__ flag) {
    int i = blockIdx.x * 256 + threadIdx.x;
    if (i >= n4) return;
    float4 v = ((const float4*)src)[i];
    if (*flag) {
        uint2 u;
        u.x = (unsigned)f2bf(v.x) | ((unsigned)f2bf(v.y) << 16);
        u.y = (unsigned)f2bf(v.z) | ((unsigned)f2bf(v.w) << 16);
        ((uint2*)dst)[i] = u;
    } else {
        ((float4*)dst)[i] = v;
    }
}

// ---------------- GEMM: C[i,n] = sum_d A[i,d] * W[n,d] ----------------
// A [4096,1024], W [1024,1024], both row-major (TN: row-dot-row, coalesced).
// A/W read directly in native dtype (flag: 1=bf16, 0=fp32). AF32=1 forces A fp32
// (used for the final projection whose A is fp32 workspace).
// ACT: 0 = silu ; 1 = gk = sigmoid(x)^(1/8) ; 2 = none
template<int ACT, int AF32>
__global__ __launch_bounds__(256) void gsa_gemm_tn(const void* __restrict__ A,
        const void* __restrict__ W, float* __restrict__ out0,
        const int* __restrict__ flag) {
    __shared__ float As[16][68];   // +4 pad keeps 16B align, 2-way-max aliasing
    __shared__ float Bs[16][68];
    const int K = 1024, N = 1024;
    const bool bf = (*flag != 0);
    int tid = threadIdx.x;
    int ntile = blockIdx.x, itile = blockIdx.y;
    int tx = tid & 15, ty = tid >> 4;
    int lrow = tid >> 2, lk = (tid & 3) << 2;
    size_t aoff = (size_t)(itile * 64 + lrow) * K + lk;
    size_t woff = (size_t)(ntile * 64 + lrow) * K + lk;
    float acc[4][4] = {};
    for (int k0 = 0; k0 < K; k0 += 16) {
        __syncthreads();
        float4 av, wv;
        if (AF32 || !bf) {
            av = *(const float4*)((const float*)A + aoff + k0);
        } else {
            ushort4 u = *(const ushort4*)((const unsigned short*)A + aoff + k0);
            av.x = bf2f(u.x); av.y = bf2f(u.y); av.z = bf2f(u.z); av.w = bf2f(u.w);
        }
        if (!bf) {
            wv = *(const float4*)((const float*)W + woff + k0);
        } else {
            ushort4 u = *(const ushort4*)((const unsigned short*)W + woff + k0);
            wv.x = bf2f(u.x); wv.y = bf2f(u.y); wv.z = bf2f(u.z); wv.w = bf2f(u.w);
        }
        As[lk + 0][lrow] = av.x; As[lk + 1][lrow] = av.y;
        As[lk + 2][lrow] = av.z; As[lk + 3][lrow] = av.w;
        Bs[lk + 0][lrow] = wv.x; Bs[lk + 1][lrow] = wv.y;
        Bs[lk + 2][lrow] = wv.z; Bs[lk + 3][lrow] = wv.w;
        __syncthreads();
        #pragma unroll
        for (int kk = 0; kk < 16; ++kk) {
            float a[4], b[4];
            #pragma unroll
            for (int i = 0; i < 4; i++) { a[i] = As[kk][ty * 4 + i]; b[i] = Bs[kk][tx * 4 + i]; }
            #pragma unroll
            for (int i = 0; i < 4; i++)
                #pragma unroll
                for (int j = 0; j < 4; j++) acc[i][j] = fmaf(a[i], b[j], acc[i][j]);
        }
    }
    int row = itile * 64 + ty * 4, col = ntile * 64 + tx * 4;
    #pragma unroll
    for (int i = 0; i < 4; i++) {
        #pragma unroll
        for (int j = 0; j < 4; j++) {
            float x = acc[i][j];
            size_t o = (size_t)(row + i) * N + (col + j);
            if (ACT == 0) {
                out0[o] = siluf(x);
            } else if (ACT == 1) {
                // log_sigmoid(x)/8 -> gk = exp(.)  (stable log1p form)
                float ls = (x >= 0.f) ? -log1pf(expf(-x)) : (x - log1pf(expf(x)));
                out0[o] = expf(0.125f * ls);
            } else {
                out0[o] = x;
            }
        }
    }
}

// ---------------- Pass 1: per-slot-column recurrence ----------------
// For each (b,h,m): S[k] <- S[k]*g_t[m] + k_t[k]*(1-g_t[m]);  ok_t[m] = q_t . S
// One wave per column m; lane holds S[4*lane .. 4*lane+3] (contiguous -> b128
// LDS reads). 4 columns/block. blockIdx%8 -> (b,h) for L2 locality.
__global__ __launch_bounds__(256) void gsa_pass1(const float* __restrict__ q,
        const float* __restrict__ k, const float* __restrict__ gk,
        float* __restrict__ ok) {
    const int TC = 16;
    __shared__ float qs[TC][256];
    __shared__ float ks[TC][256];
    __shared__ __align__(16) float gs[TC][4];
    int tid = threadIdx.x;
    int bh = blockIdx.x & 7;
    int mtile = blockIdx.x >> 3;         // 0..63
    int b = bh >> 2, h = bh & 3;
    int wave = tid >> 6, lane = tid & 63;
    int m = mtile * 4 + wave;
    size_t rb = (size_t)b * TLEN;
    const float* qb = q + rb * 1024 + h * 256;
    const float* kb = k + rb * 1024 + h * 256;
    const float* gb = gk + rb * 1024 + h * 256 + mtile * 4;
    float* okb = ok + rb * 1024 + h * 256 + m;
    float4 S = make_float4(0.f, 0.f, 0.f, 0.f);
    for (int t0 = 0; t0 < TLEN; t0 += TC) {
        __syncthreads();
        #pragma unroll
        for (int it = 0; it < 4; ++it) {
            int idx = it * 1024 + tid * 4;
            int r = idx >> 8, c = idx & 255;
            *(float4*)&qs[r][c] = *(const float4*)(qb + (size_t)(t0 + r) * 1024 + c);
            *(float4*)&ks[r][c] = *(const float4*)(kb + (size_t)(t0 + r) * 1024 + c);
        }
        if (tid < TC) *(float4*)&gs[tid][0] = *(const float4*)(gb + (size_t)(t0 + tid) * 1024);
        __syncthreads();
        for (int tt = 0; tt < TC; ++tt) {
            float g = gs[tt][wave];
            float sv = 1.f - g;
            float4 kv = *(const float4*)&ks[tt][lane * 4];
            float4 qv = *(const float4*)&qs[tt][lane * 4];
            S.x = fmaf(S.x, g, kv.x * sv);
            S.y = fmaf(S.y, g, kv.y * sv);
            S.z = fmaf(S.z, g, kv.z * sv);
            S.w = fmaf(S.w, g, kv.w * sv);
            float p = qv.x * S.x + qv.y * S.y + qv.z * S.z + qv.w * S.w;
            #pragma unroll
            for (int off = 32; off; off >>= 1) p += __shfl_xor(p, off);
            if (lane == 0) okb[(size_t)(t0 + tt) * 1024] = p;
        }
    }
}

// ---------------- softmax over M=256, in place ----------------
__global__ __launch_bounds__(256) void gsa_softmax(float* __restrict__ x) {
    int row = blockIdx.x * 4 + (threadIdx.x >> 6);   // 16384 rows of 256
    int lane = threadIdx.x & 63;
    float* p = x + (size_t)row * 256 + lane * 4;
    float4 v = *(float4*)p;
    float mx = fmaxf(fmaxf(v.x, v.y), fmaxf(v.z, v.w));
    #pragma unroll
    for (int off = 32; off; off >>= 1) mx = fmaxf(mx, __shfl_xor(mx, off));
    v.x = expf(v.x - mx); v.y = expf(v.y - mx);
    v.z = expf(v.z - mx); v.w = expf(v.w - mx);
    float sm = v.x + v.y + v.z + v.w;
    #pragma unroll
    for (int off = 32; off; off >>= 1) sm += __shfl_xor(sm, off);
    float inv = 1.f / sm;
    v.x *= inv; v.y *= inv; v.z *= inv; v.w *= inv;
    *(float4*)p = v;
}

// ---------------- Pass 2: per-value-column recurrence ----------------
// For each (b,h,v): S[m] <- S[m]*g_t[m] + (1-g_t[m])*v_t[v];  o_t[v] = qv_t . S
// Lane holds S[4*lane .. 4*lane+3] over m.
__global__ __launch_bounds__(256) void gsa_pass2(const float* __restrict__ qv,
        const float* __restrict__ v, const float* __restrict__ gk,
        float* __restrict__ ov) {
    const int TC = 8;
    __shared__ float qs[TC][256];
    __shared__ float gsh[TC][256];
    __shared__ __align__(16) float vsh[TC][4];
    int tid = threadIdx.x;
    int bh = blockIdx.x & 7;
    int vtile = blockIdx.x >> 3;
    int b = bh >> 2, h = bh & 3;
    int wave = tid >> 6, lane = tid & 63;
    int vcol = vtile * 4 + wave;
    size_t rb = (size_t)b * TLEN;
    const float* qb = qv + rb * 1024 + h * 256;
    const float* gb = gk + rb * 1024 + h * 256;
    const float* vb = v + rb * 1024 + h * 256 + vtile * 4;
    float* ob = ov + rb * 1024 + h * 256 + vcol;
    float4 S = make_float4(0.f, 0.f, 0.f, 0.f);
    for (int t0 = 0; t0 < TLEN; t0 += TC) {
        __syncthreads();
        #pragma unroll
        for (int it = 0; it < 2; ++it) {
            int idx = it * 1024 + tid * 4;
            int r = idx >> 8, c = idx & 255;
            *(float4*)&qs[r][c]  = *(const float4*)(qb + (size_t)(t0 + r) * 1024 + c);
            *(float4*)&gsh[r][c] = *(const float4*)(gb + (size_t)(t0 + r) * 1024 + c);
        }
        if (tid < TC) *(float4*)&vsh[tid][0] = *(const float4*)(vb + (size_t)(t0 + tid) * 1024);
        __syncthreads();
        for (int tt = 0; tt < TC; ++tt) {
            float vvb = vsh[tt][wave];
            float4 gv = *(const float4*)&gsh[tt][lane * 4];
            float4 av = *(const float4*)&qs[tt][lane * 4];
            S.x = fmaf(S.x, gv.x, (1.f - gv.x) * vvb);
            S.y = fmaf(S.y, gv.y, (1.f - gv.y) * vvb);
            S.z = fmaf(S.z, gv.z, (1.f - gv.z) * vvb);
            S.w = fmaf(S.w, gv.w, (1.f - gv.w) * vvb);
            float p = av.x * S.x + av.y * S.y + av.z * S.z + av.w * S.w;
            #pragma unroll
            for (int off = 32; off; off >>= 1) p += __shfl_xor(p, off);
            if (lane == 0) ob[(size_t)(t0 + tt) * 1024] = p;
        }
    }
}

// ---------------- silu -> RMSNorm(1024) -> *g_w ----------------
__global__ __launch_bounds__(256) void gsa_rmsnorm(const float* __restrict__ ov,
        const void* __restrict__ gw, const int* __restrict__ flag,
        float* __restrict__ out) {
    __shared__ float part[4];
    int row = blockIdx.x;                 // 4096 rows
    int tid = threadIdx.x;
    const float* p = ov + (size_t)row * 1024 + tid * 4;
    float4 x = *(const float4*)p;
    float y0 = siluf(x.x), y1 = siluf(x.y), y2 = siluf(x.z), y3 = siluf(x.w);
    float ssum = y0 * y0 + y1 * y1 + y2 * y2 + y3 * y3;
    #pragma unroll
    for (int off = 32; off; off >>= 1) ssum += __shfl_xor(ssum, off);
    if ((tid & 63) == 0) part[tid >> 6] = ssum;
    __syncthreads();
    float tot = part[0] + part[1] + part[2] + part[3];
    float r = rsqrtf(tot * (1.f / 1024.f) + 1e-5f);
    float4 g;
    if (*flag) {
        ushort4 u = ((const ushort4*)gw)[tid];
        g.x = bf2f(u.x); g.y = bf2f(u.y); g.z = bf2f(u.z); g.w = bf2f(u.w);
    } else {
        g = ((const float4*)gw)[tid];
    }
    float4 o;
    o.x = y0 * r * g.x; o.y = y1 * r * g.y; o.z = y2 * r * g.z; o.w = y3 * r * g.w;
    *(float4*)(out + (size_t)row * 1024 + tid * 4) = o;
}

// ---------------- launcher ----------------
extern "C" void kernel_launch(void* const* d_in, const int* in_sizes, int n_in,
                              void* d_out, int out_size, void* d_ws, size_t ws_size,
                              hipStream_t stream) {
    (void)in_sizes; (void)n_in; (void)out_size; (void)ws_size;
    const void* hs_raw = d_in[0];
    const void* wq_raw = d_in[1];
    const void* wk_raw = d_in[2];
    const void* wv_raw = d_in[3];
    const void* wf_raw = d_in[4];
    const void* gw_raw = d_in[5];
    const void* wo_raw = d_in[6];

    char* base = (char*)d_ws;
    int* flag = (int*)base;
    float* fb = (float*)(base + 256);
    const size_t NB = (size_t)NROWS * 1024;   // 4,194,304 floats per buffer
    float* Q  = fb;
    float* K  = fb + NB;
    float* V  = fb + 2 * NB;
    float* GK = fb + 3 * NB;
    float* OK = fb + 4 * NB;
    float* OV = Q;    // q dead after pass1
    float* AN = K;    // k dead after pass1
    float* FO = V;    // v dead after pass2

    gsa_detect<<<1, 1, 0, stream>>>((const unsigned*)gw_raw, flag);

    dim3 gg(16, 64);
    gsa_gemm_tn<0, 0><<<gg, 256, 0, stream>>>(hs_raw, wq_raw, Q, flag);
    gsa_gemm_tn<0, 0><<<gg, 256, 0, stream>>>(hs_raw, wk_raw, K, flag);
    gsa_gemm_tn<0, 0><<<gg, 256, 0, stream>>>(hs_raw, wv_raw, V, flag);
    gsa_gemm_tn<1, 0><<<gg, 256, 0, stream>>>(hs_raw, wf_raw, GK, flag);

    gsa_pass1<<<512, 256, 0, stream>>>(Q, K, GK, OK);
    gsa_softmax<<<4096, 256, 0, stream>>>(OK);
    gsa_pass2<<<512, 256, 0, stream>>>(OK, V, GK, OV);
    gsa_rmsnorm<<<4096, 256, 0, stream>>>(OV, gw_raw, flag, AN);
    gsa_gemm_tn<2, 1><<<gg, 256, 0, stream>>>(AN, wo_raw, FO, flag);
    gsa_emit<<<4096, 256, 0, stream>>>(FO, d_out, 1048576, flag);
}

// Round 4
// 1784.372 us; speedup vs baseline: 1.1705x; 1.1705x over previous
//
#include <hip/hip_runtime.h>
#include <math.h>

// Gated Slot Attention forward, MI355X round 3.
// B=2, T=2048, D=1024, H=4, DK=DV=M=256. Row width H*256 = 1024 everywhere.
// Projections: bf16 MFMA (m97-style 128x128 tile, global_load_lds 16B staging).
// Recurrences: one wave per state column, DPP wave-reduction (no DS ops in loop).
// R3 fix: update_dpp ctrl/masks must be compile-time constants -> template params.
#define TLEN 2048
#define NROWS 4096   // B*T

typedef unsigned short u16;
typedef __attribute__((ext_vector_type(8))) short bf16x8;
typedef __attribute__((ext_vector_type(4))) float f32x4;

// ---------------- dtype helpers ----------------
__device__ __forceinline__ float bf2f(u16 u) {
    unsigned v = ((unsigned)u) << 16; float f; __builtin_memcpy(&f, &v, 4); return f;
}
__device__ __forceinline__ u16 f2bf(float x) {
    unsigned u; __builtin_memcpy(&u, &x, 4);
    u += 0x7FFFu + ((u >> 16) & 1u);            // round-to-nearest-even
    return (u16)(u >> 16);
}
__device__ __forceinline__ float siluf(float x) { return x / (1.f + expf(-x)); }

// DPP wave64 sum: result valid in lane 63. gfx9 sequence (row_shr + row_bcast).
template<int CTRL, int RM>
__device__ __forceinline__ float dpp_add(float x) {
    int t = __builtin_amdgcn_update_dpp(0, __builtin_bit_cast(int, x), CTRL, RM, 0xf, true);
    return x + __builtin_bit_cast(float, t);
}
__device__ __forceinline__ float wave_red_add(float x) {
    x = dpp_add<0x111, 0xf>(x);   // row_shr:1
    x = dpp_add<0x112, 0xf>(x);   // row_shr:2
    x = dpp_add<0x114, 0xf>(x);   // row_shr:4
    x = dpp_add<0x118, 0xf>(x);   // row_shr:8  -> lane 15 of each row16 has row sum
    x = dpp_add<0x142, 0xa>(x);   // row_bcast:15 into rows 1,3
    x = dpp_add<0x143, 0xc>(x);   // row_bcast:31 into rows 2,3 -> lane 63 total
    return x;
}
__device__ __forceinline__ float readlane_f(float v, int l) {
    return __builtin_bit_cast(float, __builtin_amdgcn_readlane(__builtin_bit_cast(int, v), l));
}

// g_w is exactly ones(1024): first word 0x3F800000 (fp32) vs 0x3F803F80 (bf16x2).
__global__ void gsa_detect(const unsigned* __restrict__ gw, int* __restrict__ flag) {
    *flag = (gw[0] == 0x3F803F80u) ? 1 : 0;
}

// Canonicalize an input to bf16 (identity copy when already bf16). n8 = elems/8.
__global__ __launch_bounds__(256) void gsa_tobf16(const void* __restrict__ src,
        u16* __restrict__ dst, int n8, const int* __restrict__ flag) {
    int i = blockIdx.x * 256 + threadIdx.x;
    if (i >= n8) return;
    if (*flag) {
        ((uint4*)dst)[i] = ((const uint4*)src)[i];
    } else {
        float4 a = ((const float4*)src)[2 * i];
        float4 b = ((const float4*)src)[2 * i + 1];
        uint4 o;
        o.x = (unsigned)f2bf(a.x) | ((unsigned)f2bf(a.y) << 16);
        o.y = (unsigned)f2bf(a.z) | ((unsigned)f2bf(a.w) << 16);
        o.z = (unsigned)f2bf(b.x) | ((unsigned)f2bf(b.y) << 16);
        o.w = (unsigned)f2bf(b.z) | ((unsigned)f2bf(b.w) << 16);
        ((uint4*)dst)[i] = o;
    }
}

__global__ __launch_bounds__(256) void gsa_emit(const float* __restrict__ src,
        void* __restrict__ dst, int n4, const int* __restrict__ flag) {
    int i = blockIdx.x * 256 + threadIdx.x;
    if (i >= n4) return;
    float4 v = ((const float4*)src)[i];
    if (*flag) {
        uint2 u;
        u.x = (unsigned)f2bf(v.x) | ((unsigned)f2bf(v.y) << 16);
        u.y = (unsigned)f2bf(v.z) | ((unsigned)f2bf(v.w) << 16);
        ((uint2*)dst)[i] = u;
    } else {
        ((float4*)dst)[i] = v;
    }
}

// ---------------- MFMA GEMM: C[i,n] = sum_d A[i,d] * W[n,d] ----------------
// A [4096,1024] bf16 row-major, W [1024,1024] bf16 row-major (both K-contiguous).
// 128x128 block tile, BK=32, 4 waves in 2x2, each wave 64x64 via 4x4 mfma
// 16x16x32 tiles. Staging via global_load_lds width=16 (wave-uniform base+lane*16).
// sel = blockIdx.x>>3 picks W/out/act (fused QKVF); act: 0=silu 1=gate 2=none.
#define GLOAD_LDS16(g, l) \
    __builtin_amdgcn_global_load_lds((const __attribute__((address_space(1))) void*)(g), \
                                     (__attribute__((address_space(3))) void*)(l), 16, 0, 0)

__global__ __launch_bounds__(256) void gsa_gemm_mfma(const u16* __restrict__ A,
        const u16* __restrict__ W0, const u16* __restrict__ W1,
        const u16* __restrict__ W2, const u16* __restrict__ W3,
        float* __restrict__ O0, float* __restrict__ O1,
        float* __restrict__ O2, float* __restrict__ O3, int actpack) {
    __shared__ u16 As[128 * 32];
    __shared__ u16 Bs[128 * 32];
    int tid = threadIdx.x;
    int sel = blockIdx.x >> 3;
    int ntile = blockIdx.x & 7;
    int mtile = blockIdx.y;
    const u16* W = (sel == 0) ? W0 : (sel == 1) ? W1 : (sel == 2) ? W2 : W3;
    float* Out   = (sel == 0) ? O0 : (sel == 1) ? O1 : (sel == 2) ? O2 : O3;
    int act = (actpack >> (sel * 8)) & 0xff;
    int w = tid >> 6, lane = tid & 63;
    int wm = w >> 1, wn = w & 1;
    int m0 = wm * 64, n0 = wn * 64;
    // staging source rows for this lane (2 calls each for A and B)
    int srow = w * 32 + (lane >> 2);          // +0 and +16
    int scol = (lane & 3) * 8;                // ushort offset within BK=32
    const u16* Abase = A + (size_t)(mtile * 128 + srow) * 1024 + scol;
    const u16* Wbase = W + (size_t)(ntile * 128 + srow) * 1024 + scol;
    u16* AsDst0 = &As[(w * 32) * 32];         // lane L lands at +L*8 ushorts
    u16* BsDst0 = &Bs[(w * 32) * 32];
    f32x4 acc[4][4];
    #pragma unroll
    for (int i = 0; i < 4; i++)
        #pragma unroll
        for (int j = 0; j < 4; j++) acc[i][j] = (f32x4){0.f, 0.f, 0.f, 0.f};
    int frow = lane & 15, fq = lane >> 4;     // fragment row/quad
    for (int k0 = 0; k0 < 1024; k0 += 32) {
        __syncthreads();
        GLOAD_LDS16(Abase + k0, AsDst0);
        GLOAD_LDS16(Abase + k0 + (size_t)16 * 1024, AsDst0 + 16 * 32);
        GLOAD_LDS16(Wbase + k0, BsDst0);
        GLOAD_LDS16(Wbase + k0 + (size_t)16 * 1024, BsDst0 + 16 * 32);
        __syncthreads();
        bf16x8 af[4], bfv[4];
        #pragma unroll
        for (int mt = 0; mt < 4; mt++)
            af[mt] = *(const bf16x8*)&As[(m0 + mt * 16 + frow) * 32 + fq * 8];
        #pragma unroll
        for (int nt = 0; nt < 4; nt++)
            bfv[nt] = *(const bf16x8*)&Bs[(n0 + nt * 16 + frow) * 32 + fq * 8];
        #pragma unroll
        for (int mt = 0; mt < 4; mt++)
            #pragma unroll
            for (int nt = 0; nt < 4; nt++)
                acc[mt][nt] = __builtin_amdgcn_mfma_f32_16x16x32_bf16(
                    af[mt], bfv[nt], acc[mt][nt], 0, 0, 0);
    }
    // epilogue: C/D layout col=lane&15, row=quad*4+reg
    #pragma unroll
    for (int mt = 0; mt < 4; mt++) {
        #pragma unroll
        for (int nt = 0; nt < 4; nt++) {
            #pragma unroll
            for (int r = 0; r < 4; r++) {
                float x = acc[mt][nt][r];
                int grow = mtile * 128 + m0 + mt * 16 + fq * 4 + r;
                int gcol = ntile * 128 + n0 + nt * 16 + frow;
                float val;
                if (act == 0) val = siluf(x);
                else if (act == 1) {
                    float ls = (x >= 0.f) ? -log1pf(expf(-x)) : (x - log1pf(expf(x)));
                    val = expf(0.125f * ls);   // gk = sigmoid(x)^(1/8)
                } else val = x;
                Out[(size_t)grow * 1024 + gcol] = val;
            }
        }
    }
}

// ---------------- Pass 1: per-slot-column recurrence ----------------
// (b,h,m): S[k] <- S[k]*g_t[m] + k_t[k]*(1-g_t[m]); ok_t[m] = q_t . S
// One wave per m; lane holds S[4*lane..+3]. No DS ops: direct global loads,
// readlane broadcast, DPP reduction. blockIdx&7 -> (b,h) for XCD-L2 locality.
__global__ __launch_bounds__(256) void gsa_pass1(const float* __restrict__ q,
        const float* __restrict__ k, const float* __restrict__ gk,
        float* __restrict__ ok) {
    int tid = threadIdx.x;
    int bh = blockIdx.x & 7;
    int mtile = blockIdx.x >> 3;         // 0..63
    int b = bh >> 2, h = bh & 3;
    int wave = tid >> 6, lane = tid & 63;
    int m = mtile * 4 + wave;
    size_t rb = (size_t)b * TLEN;
    const float* qb = q + rb * 1024 + h * 256;
    const float* kb = k + rb * 1024 + h * 256;
    const float* gb = gk + rb * 1024 + h * 256 + m;
    float* okb = ok + rb * 1024 + h * 256 + m;
    float4 S = make_float4(0.f, 0.f, 0.f, 0.f);
    for (int t0 = 0; t0 < TLEN; t0 += 16) {
        float gl = gb[(size_t)(t0 + (lane & 15)) * 1024];
        #pragma unroll
        for (int tt = 0; tt < 16; ++tt) {
            float g = readlane_f(gl, tt);
            float sv = 1.f - g;
            float4 qv = *(const float4*)(qb + (size_t)(t0 + tt) * 1024 + lane * 4);
            float4 kv = *(const float4*)(kb + (size_t)(t0 + tt) * 1024 + lane * 4);
            S.x = fmaf(S.x, g, kv.x * sv);
            S.y = fmaf(S.y, g, kv.y * sv);
            S.z = fmaf(S.z, g, kv.z * sv);
            S.w = fmaf(S.w, g, kv.w * sv);
            float p = qv.x * S.x + qv.y * S.y + qv.z * S.z + qv.w * S.w;
            float r = wave_red_add(p);
            if (lane == 63) okb[(size_t)(t0 + tt) * 1024] = r;
        }
    }
}

// ---------------- softmax over M=256, in place ----------------
__global__ __launch_bounds__(256) void gsa_softmax(float* __restrict__ x) {
    int row = blockIdx.x * 4 + (threadIdx.x >> 6);   // 16384 rows of 256
    int lane = threadIdx.x & 63;
    float* p = x + (size_t)row * 256 + lane * 4;
    float4 v = *(float4*)p;
    float mx = fmaxf(fmaxf(v.x, v.y), fmaxf(v.z, v.w));
    #pragma unroll
    for (int off = 32; off; off >>= 1) mx = fmaxf(mx, __shfl_xor(mx, off));
    v.x = expf(v.x - mx); v.y = expf(v.y - mx);
    v.z = expf(v.z - mx); v.w = expf(v.w - mx);
    float sm = v.x + v.y + v.z + v.w;
    #pragma unroll
    for (int off = 32; off; off >>= 1) sm += __shfl_xor(sm, off);
    float inv = 1.f / sm;
    v.x *= inv; v.y *= inv; v.z *= inv; v.w *= inv;
    *(float4*)p = v;
}

// ---------------- Pass 2: per-value-column recurrence ----------------
// (b,h,v): S[m] <- S[m]*g_t[m] + (1-g_t[m])*v_t[v]; o_t[v] = qv_t . S
__global__ __launch_bounds__(256) void gsa_pass2(const float* __restrict__ qv,
        const float* __restrict__ v, const float* __restrict__ gk,
        float* __restrict__ ov) {
    int tid = threadIdx.x;
    int bh = blockIdx.x & 7;
    int vtile = blockIdx.x >> 3;
    int b = bh >> 2, h = bh & 3;
    int wave = tid >> 6, lane = tid & 63;
    int vcol = vtile * 4 + wave;
    size_t rb = (size_t)b * TLEN;
    const float* qb = qv + rb * 1024 + h * 256;
    const float* gb = gk + rb * 1024 + h * 256;
    const float* vb = v + rb * 1024 + h * 256 + vcol;
    float* ob = ov + rb * 1024 + h * 256 + vcol;
    float4 S = make_float4(0.f, 0.f, 0.f, 0.f);
    for (int t0 = 0; t0 < TLEN; t0 += 16) {
        float vl = vb[(size_t)(t0 + (lane & 15)) * 1024];
        #pragma unroll
        for (int tt = 0; tt < 16; ++tt) {
            float vvt = readlane_f(vl, tt);
            float4 g4 = *(const float4*)(gb + (size_t)(t0 + tt) * 1024 + lane * 4);
            float4 a4 = *(const float4*)(qb + (size_t)(t0 + tt) * 1024 + lane * 4);
            S.x = fmaf(S.x, g4.x, (1.f - g4.x) * vvt);
            S.y = fmaf(S.y, g4.y, (1.f - g4.y) * vvt);
            S.z = fmaf(S.z, g4.z, (1.f - g4.z) * vvt);
            S.w = fmaf(S.w, g4.w, (1.f - g4.w) * vvt);
            float p = a4.x * S.x + a4.y * S.y + a4.z * S.z + a4.w * S.w;
            float r = wave_red_add(p);
            if (lane == 63) ob[(size_t)(t0 + tt) * 1024] = r;
        }
    }
}

// ---------------- silu -> RMSNorm(1024) -> *g_w -> bf16 ----------------
__global__ __launch_bounds__(256) void gsa_rmsnorm(const float* __restrict__ ov,
        const void* __restrict__ gw, const int* __restrict__ flag,
        u16* __restrict__ out) {
    __shared__ float part[4];
    int row = blockIdx.x;                 // 4096 rows
    int tid = threadIdx.x;
    const float* p = ov + (size_t)row * 1024 + tid * 4;
    float4 x = *(const float4*)p;
    float y0 = siluf(x.x), y1 = siluf(x.y), y2 = siluf(x.z), y3 = siluf(x.w);
    float ssum = y0 * y0 + y1 * y1 + y2 * y2 + y3 * y3;
    #pragma unroll
    for (int off = 32; off; off >>= 1) ssum += __shfl_xor(ssum, off);
    if ((tid & 63) == 0) part[tid >> 6] = ssum;
    __syncthreads();
    float tot = part[0] + part[1] + part[2] + part[3];
    float r = rsqrtf(tot * (1.f / 1024.f) + 1e-5f);
    float4 g;
    if (*flag) {
        ushort4 u = ((const ushort4*)gw)[tid];
        g.x = bf2f(u.x); g.y = bf2f(u.y); g.z = bf2f(u.z); g.w = bf2f(u.w);
    } else {
        g = ((const float4*)gw)[tid];
    }
    ushort4 o;
    o.x = f2bf(y0 * r * g.x); o.y = f2bf(y1 * r * g.y);
    o.z = f2bf(y2 * r * g.z); o.w = f2bf(y3 * r * g.w);
    ((ushort4*)(out + (size_t)row * 1024))[tid] = o;
}

// ---------------- launcher ----------------
extern "C" void kernel_launch(void* const* d_in, const int* in_sizes, int n_in,
                              void* d_out, int out_size, void* d_ws, size_t ws_size,
                              hipStream_t stream) {
    (void)in_sizes; (void)n_in; (void)out_size; (void)ws_size;
    const void* hs_raw = d_in[0];
    const void* wq_raw = d_in[1];
    const void* wk_raw = d_in[2];
    const void* wv_raw = d_in[3];
    const void* wf_raw = d_in[4];
    const void* gw_raw = d_in[5];
    const void* wo_raw = d_in[6];

    char* base = (char*)d_ws;
    int* flag = (int*)base;
    float* fb = (float*)(base + 256);
    const size_t NB = (size_t)NROWS * 1024;   // floats per big buffer
    float* Q  = fb;
    float* K  = fb + NB;
    float* V  = fb + 2 * NB;
    float* GK = fb + 3 * NB;
    float* OK = fb + 4 * NB;
    u16* Wb  = (u16*)(fb + 5 * NB);           // 5 x 1,048,576 bf16 weights
    u16* WQb = Wb;
    u16* WKb = Wb + 1048576;
    u16* WVb = Wb + 2 * 1048576;
    u16* WFb = Wb + 3 * 1048576;
    u16* WOb = Wb + 4 * 1048576;
    u16* HSb = (u16*)OK;   // staged bf16 hidden lives in OK's dead window
    float* OV = Q;         // q dead after pass1
    u16* AN   = (u16*)K;   // k dead after pass1
    float* FO = V;         // v dead after pass2

    gsa_detect<<<1, 1, 0, stream>>>((const unsigned*)gw_raw, flag);
    gsa_tobf16<<<2048, 256, 0, stream>>>(hs_raw, HSb, 524288, flag);
    gsa_tobf16<<<512, 256, 0, stream>>>(wq_raw, WQb, 131072, flag);
    gsa_tobf16<<<512, 256, 0, stream>>>(wk_raw, WKb, 131072, flag);
    gsa_tobf16<<<512, 256, 0, stream>>>(wv_raw, WVb, 131072, flag);
    gsa_tobf16<<<512, 256, 0, stream>>>(wf_raw, WFb, 131072, flag);
    gsa_tobf16<<<512, 256, 0, stream>>>(wo_raw, WOb, 131072, flag);

    // fused QKVF: grid.x = 4 projections x 8 ntiles; acts {silu,silu,silu,gate}
    gsa_gemm_mfma<<<dim3(32, 32), 256, 0, stream>>>(HSb, WQb, WKb, WVb, WFb,
                                                    Q, K, V, GK, 0x01000000);
    gsa_pass1<<<512, 256, 0, stream>>>(Q, K, GK, OK);
    gsa_softmax<<<4096, 256, 0, stream>>>(OK);
    gsa_pass2<<<512, 256, 0, stream>>>(OK, V, GK, OV);
    gsa_rmsnorm<<<4096, 256, 0, stream>>>(OV, gw_raw, flag, AN);
    // Wo: grid.x = 8 -> sel always 0; act none
    gsa_gemm_mfma<<<dim3(8, 32), 256, 0, stream>>>(AN, WOb, WOb, WOb, WOb,
                                                   FO, FO, FO, FO, 0x02020202);
    gsa_emit<<<4096, 256, 0, stream>>>(FO, d_out, 1048576, flag);
}

// Round 5
// 1029.035 us; speedup vs baseline: 2.0297x; 1.7340x over previous
//
#include <hip/hip_runtime.h>
#include <math.h>

// Gated Slot Attention forward, MI355X round 4.
// B=2, T=2048, D=1024, H=4, DK=DV=M=256. Row width H*256 = 1024 everywhere.
// Projections: bf16 MFMA (128x128 tile, global_load_lds 16B staging).
// Recurrences: one wave per state column, DPP reduction, and (new in R4)
// software-pipelined register prefetch: 8-step blocks, load block n+1 while
// computing block n. R3's VGPR_Count=20 showed zero prefetch distance ->
// per-step L2 latency exposed (VALUBusy 26%).
#define TLEN 2048
#define NROWS 4096   // B*T

typedef unsigned short u16;
typedef __attribute__((ext_vector_type(8))) short bf16x8;
typedef __attribute__((ext_vector_type(4))) float f32x4;

// ---------------- dtype helpers ----------------
__device__ __forceinline__ float bf2f(u16 u) {
    unsigned v = ((unsigned)u) << 16; float f; __builtin_memcpy(&f, &v, 4); return f;
}
__device__ __forceinline__ u16 f2bf(float x) {
    unsigned u; __builtin_memcpy(&u, &x, 4);
    u += 0x7FFFu + ((u >> 16) & 1u);            // round-to-nearest-even
    return (u16)(u >> 16);
}
__device__ __forceinline__ float siluf(float x) { return x / (1.f + expf(-x)); }

// DPP wave64 sum: result valid in lane 63. gfx9 sequence (row_shr + row_bcast).
template<int CTRL, int RM>
__device__ __forceinline__ float dpp_add(float x) {
    int t = __builtin_amdgcn_update_dpp(0, __builtin_bit_cast(int, x), CTRL, RM, 0xf, true);
    return x + __builtin_bit_cast(float, t);
}
__device__ __forceinline__ float wave_red_add(float x) {
    x = dpp_add<0x111, 0xf>(x);   // row_shr:1
    x = dpp_add<0x112, 0xf>(x);   // row_shr:2
    x = dpp_add<0x114, 0xf>(x);   // row_shr:4
    x = dpp_add<0x118, 0xf>(x);   // row_shr:8  -> lane 15 of each row16 has row sum
    x = dpp_add<0x142, 0xa>(x);   // row_bcast:15 into rows 1,3
    x = dpp_add<0x143, 0xc>(x);   // row_bcast:31 into rows 2,3 -> lane 63 total
    return x;
}
__device__ __forceinline__ float readlane_f(float v, int l) {
    return __builtin_bit_cast(float, __builtin_amdgcn_readlane(__builtin_bit_cast(int, v), l));
}

// g_w is exactly ones(1024): first word 0x3F800000 (fp32) vs 0x3F803F80 (bf16x2).
__global__ void gsa_detect(const unsigned* __restrict__ gw, int* __restrict__ flag) {
    *flag = (gw[0] == 0x3F803F80u) ? 1 : 0;
}

// Canonicalize an input to bf16 (identity copy when already bf16). n8 = elems/8.
__global__ __launch_bounds__(256) void gsa_tobf16(const void* __restrict__ src,
        u16* __restrict__ dst, int n8, const int* __restrict__ flag) {
    int i = blockIdx.x * 256 + threadIdx.x;
    if (i >= n8) return;
    if (*flag) {
        ((uint4*)dst)[i] = ((const uint4*)src)[i];
    } else {
        float4 a = ((const float4*)src)[2 * i];
        float4 b = ((const float4*)src)[2 * i + 1];
        uint4 o;
        o.x = (unsigned)f2bf(a.x) | ((unsigned)f2bf(a.y) << 16);
        o.y = (unsigned)f2bf(a.z) | ((unsigned)f2bf(a.w) << 16);
        o.z = (unsigned)f2bf(b.x) | ((unsigned)f2bf(b.y) << 16);
        o.w = (unsigned)f2bf(b.z) | ((unsigned)f2bf(b.w) << 16);
        ((uint4*)dst)[i] = o;
    }
}

__global__ __launch_bounds__(256) void gsa_emit(const float* __restrict__ src,
        void* __restrict__ dst, int n4, const int* __restrict__ flag) {
    int i = blockIdx.x * 256 + threadIdx.x;
    if (i >= n4) return;
    float4 v = ((const float4*)src)[i];
    if (*flag) {
        uint2 u;
        u.x = (unsigned)f2bf(v.x) | ((unsigned)f2bf(v.y) << 16);
        u.y = (unsigned)f2bf(v.z) | ((unsigned)f2bf(v.w) << 16);
        ((uint2*)dst)[i] = u;
    } else {
        ((float4*)dst)[i] = v;
    }
}

// ---------------- MFMA GEMM: C[i,n] = sum_d A[i,d] * W[n,d] ----------------
#define GLOAD_LDS16(g, l) \
    __builtin_amdgcn_global_load_lds((const __attribute__((address_space(1))) void*)(g), \
                                     (__attribute__((address_space(3))) void*)(l), 16, 0, 0)

__global__ __launch_bounds__(256) void gsa_gemm_mfma(const u16* __restrict__ A,
        const u16* __restrict__ W0, const u16* __restrict__ W1,
        const u16* __restrict__ W2, const u16* __restrict__ W3,
        float* __restrict__ O0, float* __restrict__ O1,
        float* __restrict__ O2, float* __restrict__ O3, int actpack) {
    __shared__ u16 As[128 * 32];
    __shared__ u16 Bs[128 * 32];
    int tid = threadIdx.x;
    int sel = blockIdx.x >> 3;
    int ntile = blockIdx.x & 7;
    int mtile = blockIdx.y;
    const u16* W = (sel == 0) ? W0 : (sel == 1) ? W1 : (sel == 2) ? W2 : W3;
    float* Out   = (sel == 0) ? O0 : (sel == 1) ? O1 : (sel == 2) ? O2 : O3;
    int act = (actpack >> (sel * 8)) & 0xff;
    int w = tid >> 6, lane = tid & 63;
    int wm = w >> 1, wn = w & 1;
    int m0 = wm * 64, n0 = wn * 64;
    int srow = w * 32 + (lane >> 2);          // +0 and +16
    int scol = (lane & 3) * 8;                // ushort offset within BK=32
    const u16* Abase = A + (size_t)(mtile * 128 + srow) * 1024 + scol;
    const u16* Wbase = W + (size_t)(ntile * 128 + srow) * 1024 + scol;
    u16* AsDst0 = &As[(w * 32) * 32];
    u16* BsDst0 = &Bs[(w * 32) * 32];
    f32x4 acc[4][4];
    #pragma unroll
    for (int i = 0; i < 4; i++)
        #pragma unroll
        for (int j = 0; j < 4; j++) acc[i][j] = (f32x4){0.f, 0.f, 0.f, 0.f};
    int frow = lane & 15, fq = lane >> 4;
    for (int k0 = 0; k0 < 1024; k0 += 32) {
        __syncthreads();
        GLOAD_LDS16(Abase + k0, AsDst0);
        GLOAD_LDS16(Abase + k0 + (size_t)16 * 1024, AsDst0 + 16 * 32);
        GLOAD_LDS16(Wbase + k0, BsDst0);
        GLOAD_LDS16(Wbase + k0 + (size_t)16 * 1024, BsDst0 + 16 * 32);
        __syncthreads();
        bf16x8 af[4], bfv[4];
        #pragma unroll
        for (int mt = 0; mt < 4; mt++)
            af[mt] = *(const bf16x8*)&As[(m0 + mt * 16 + frow) * 32 + fq * 8];
        #pragma unroll
        for (int nt = 0; nt < 4; nt++)
            bfv[nt] = *(const bf16x8*)&Bs[(n0 + nt * 16 + frow) * 32 + fq * 8];
        #pragma unroll
        for (int mt = 0; mt < 4; mt++)
            #pragma unroll
            for (int nt = 0; nt < 4; nt++)
                acc[mt][nt] = __builtin_amdgcn_mfma_f32_16x16x32_bf16(
                    af[mt], bfv[nt], acc[mt][nt], 0, 0, 0);
    }
    #pragma unroll
    for (int mt = 0; mt < 4; mt++) {
        #pragma unroll
        for (int nt = 0; nt < 4; nt++) {
            #pragma unroll
            for (int r = 0; r < 4; r++) {
                float x = acc[mt][nt][r];
                int grow = mtile * 128 + m0 + mt * 16 + fq * 4 + r;
                int gcol = ntile * 128 + n0 + nt * 16 + frow;
                float val;
                if (act == 0) val = siluf(x);
                else if (act == 1) {
                    float ls = (x >= 0.f) ? -log1pf(expf(-x)) : (x - log1pf(expf(x)));
                    val = expf(0.125f * ls);   // gk = sigmoid(x)^(1/8)
                } else val = x;
                Out[(size_t)grow * 1024 + gcol] = val;
            }
        }
    }
}

// ---------------- Pass 1: per-slot-column recurrence (pipelined) ----------------
// (b,h,m): S[k] <- S[k]*g_t[m] + k_t[k]*(1-g_t[m]); ok_t[m] = q_t . S
// One wave per m; lane holds S[4*lane..+3]. 8-step register blocks, prefetch
// next block's 17 loads while computing current block (register+DPP only).
__device__ __forceinline__ void p1_load(const float* __restrict__ qb,
        const float* __restrict__ kb, const float* __restrict__ gbm,
        int t0, int lane, float4* qv, float4* kv, float& gs) {
    #pragma unroll
    for (int i = 0; i < 8; i++) {
        qv[i] = *(const float4*)(qb + (size_t)(t0 + i) * 1024 + lane * 4);
        kv[i] = *(const float4*)(kb + (size_t)(t0 + i) * 1024 + lane * 4);
    }
    gs = gbm[(size_t)(t0 + (lane & 7)) * 1024];
}
__device__ __forceinline__ void p1_comp(const float4* qv, const float4* kv,
        float gs, float4& S, float* __restrict__ okb, int t0, int lane) {
    #pragma unroll
    for (int tt = 0; tt < 8; tt++) {
        float g = readlane_f(gs, tt);
        float sv = 1.f - g;
        S.x = fmaf(S.x, g, kv[tt].x * sv);
        S.y = fmaf(S.y, g, kv[tt].y * sv);
        S.z = fmaf(S.z, g, kv[tt].z * sv);
        S.w = fmaf(S.w, g, kv[tt].w * sv);
        float p = qv[tt].x * S.x + qv[tt].y * S.y + qv[tt].z * S.z + qv[tt].w * S.w;
        float r = wave_red_add(p);
        if (lane == 63) okb[(size_t)(t0 + tt) * 1024] = r;
    }
}
__global__ __launch_bounds__(256) void gsa_pass1(const float* __restrict__ q,
        const float* __restrict__ k, const float* __restrict__ gk,
        float* __restrict__ ok) {
    int tid = threadIdx.x;
    int bh = blockIdx.x & 7;
    int mtile = blockIdx.x >> 3;         // 0..63
    int b = bh >> 2, h = bh & 3;
    int wave = tid >> 6, lane = tid & 63;
    int m = mtile * 4 + wave;
    size_t rb = (size_t)b * TLEN;
    const float* qb = q + rb * 1024 + h * 256;
    const float* kb = k + rb * 1024 + h * 256;
    const float* gbm = gk + rb * 1024 + h * 256 + m;
    float* okb = ok + rb * 1024 + h * 256 + m;
    float4 S = make_float4(0.f, 0.f, 0.f, 0.f);
    float4 qa[8], ka[8]; float ga;
    p1_load(qb, kb, gbm, 0, lane, qa, ka, ga);
    for (int t0 = 0; t0 < TLEN; t0 += 16) {
        float4 qn[8], kn[8]; float gn;
        p1_load(qb, kb, gbm, t0 + 8, lane, qn, kn, gn);
        p1_comp(qa, ka, ga, S, okb, t0, lane);
        if (t0 + 16 < TLEN) p1_load(qb, kb, gbm, t0 + 16, lane, qa, ka, ga);
        p1_comp(qn, kn, gn, S, okb, t0 + 8, lane);
    }
}

// ---------------- softmax over M=256, in place ----------------
__global__ __launch_bounds__(256) void gsa_softmax(float* __restrict__ x) {
    int row = blockIdx.x * 4 + (threadIdx.x >> 6);   // 16384 rows of 256
    int lane = threadIdx.x & 63;
    float* p = x + (size_t)row * 256 + lane * 4;
    float4 v = *(float4*)p;
    float mx = fmaxf(fmaxf(v.x, v.y), fmaxf(v.z, v.w));
    #pragma unroll
    for (int off = 32; off; off >>= 1) mx = fmaxf(mx, __shfl_xor(mx, off));
    v.x = expf(v.x - mx); v.y = expf(v.y - mx);
    v.z = expf(v.z - mx); v.w = expf(v.w - mx);
    float sm = v.x + v.y + v.z + v.w;
    #pragma unroll
    for (int off = 32; off; off >>= 1) sm += __shfl_xor(sm, off);
    float inv = 1.f / sm;
    v.x *= inv; v.y *= inv; v.z *= inv; v.w *= inv;
    *(float4*)p = v;
}

// ---------------- Pass 2: per-value-column recurrence (pipelined) ----------------
// (b,h,v): S[m] <- S[m]*g_t[m] + (1-g_t[m])*v_t[v]; o_t[v] = qv_t . S
__device__ __forceinline__ void p2_load(const float* __restrict__ qb,
        const float* __restrict__ gb, const float* __restrict__ vbc,
        int t0, int lane, float4* av, float4* gv, float& vs) {
    #pragma unroll
    for (int i = 0; i < 8; i++) {
        av[i] = *(const float4*)(qb + (size_t)(t0 + i) * 1024 + lane * 4);
        gv[i] = *(const float4*)(gb + (size_t)(t0 + i) * 1024 + lane * 4);
    }
    vs = vbc[(size_t)(t0 + (lane & 7)) * 1024];
}
__device__ __forceinline__ void p2_comp(const float4* av, const float4* gv,
        float vs, float4& S, float* __restrict__ ob, int t0, int lane) {
    #pragma unroll
    for (int tt = 0; tt < 8; tt++) {
        float vvt = readlane_f(vs, tt);
        float4 g4 = gv[tt];
        float4 a4 = av[tt];
        S.x = fmaf(S.x, g4.x, (1.f - g4.x) * vvt);
        S.y = fmaf(S.y, g4.y, (1.f - g4.y) * vvt);
        S.z = fmaf(S.z, g4.z, (1.f - g4.z) * vvt);
        S.w = fmaf(S.w, g4.w, (1.f - g4.w) * vvt);
        float p = a4.x * S.x + a4.y * S.y + a4.z * S.z + a4.w * S.w;
        float r = wave_red_add(p);
        if (lane == 63) ob[(size_t)(t0 + tt) * 1024] = r;
    }
}
__global__ __launch_bounds__(256) void gsa_pass2(const float* __restrict__ qv,
        const float* __restrict__ v, const float* __restrict__ gk,
        float* __restrict__ ov) {
    int tid = threadIdx.x;
    int bh = blockIdx.x & 7;
    int vtile = blockIdx.x >> 3;
    int b = bh >> 2, h = bh & 3;
    int wave = tid >> 6, lane = tid & 63;
    int vcol = vtile * 4 + wave;
    size_t rb = (size_t)b * TLEN;
    const float* qb = qv + rb * 1024 + h * 256;
    const float* gb = gk + rb * 1024 + h * 256;
    const float* vbc = v + rb * 1024 + h * 256 + vcol;
    float* ob = ov + rb * 1024 + h * 256 + vcol;
    float4 S = make_float4(0.f, 0.f, 0.f, 0.f);
    float4 aa[8], ga4[8]; float va;
    p2_load(qb, gb, vbc, 0, lane, aa, ga4, va);
    for (int t0 = 0; t0 < TLEN; t0 += 16) {
        float4 an[8], gn4[8]; float vn;
        p2_load(qb, gb, vbc, t0 + 8, lane, an, gn4, vn);
        p2_comp(aa, ga4, va, S, ob, t0, lane);
        if (t0 + 16 < TLEN) p2_load(qb, gb, vbc, t0 + 16, lane, aa, ga4, va);
        p2_comp(an, gn4, vn, S, ob, t0 + 8, lane);
    }
}

// ---------------- silu -> RMSNorm(1024) -> *g_w -> bf16 ----------------
__global__ __launch_bounds__(256) void gsa_rmsnorm(const float* __restrict__ ov,
        const void* __restrict__ gw, const int* __restrict__ flag,
        u16* __restrict__ out) {
    __shared__ float part[4];
    int row = blockIdx.x;                 // 4096 rows
    int tid = threadIdx.x;
    const float* p = ov + (size_t)row * 1024 + tid * 4;
    float4 x = *(const float4*)p;
    float y0 = siluf(x.x), y1 = siluf(x.y), y2 = siluf(x.z), y3 = siluf(x.w);
    float ssum = y0 * y0 + y1 * y1 + y2 * y2 + y3 * y3;
    #pragma unroll
    for (int off = 32; off; off >>= 1) ssum += __shfl_xor(ssum, off);
    if ((tid & 63) == 0) part[tid >> 6] = ssum;
    __syncthreads();
    float tot = part[0] + part[1] + part[2] + part[3];
    float r = rsqrtf(tot * (1.f / 1024.f) + 1e-5f);
    float4 g;
    if (*flag) {
        ushort4 u = ((const ushort4*)gw)[tid];
        g.x = bf2f(u.x); g.y = bf2f(u.y); g.z = bf2f(u.z); g.w = bf2f(u.w);
    } else {
        g = ((const float4*)gw)[tid];
    }
    ushort4 o;
    o.x = f2bf(y0 * r * g.x); o.y = f2bf(y1 * r * g.y);
    o.z = f2bf(y2 * r * g.z); o.w = f2bf(y3 * r * g.w);
    ((ushort4*)(out + (size_t)row * 1024))[tid] = o;
}

// ---------------- launcher ----------------
extern "C" void kernel_launch(void* const* d_in, const int* in_sizes, int n_in,
                              void* d_out, int out_size, void* d_ws, size_t ws_size,
                              hipStream_t stream) {
    (void)in_sizes; (void)n_in; (void)out_size; (void)ws_size;
    const void* hs_raw = d_in[0];
    const void* wq_raw = d_in[1];
    const void* wk_raw = d_in[2];
    const void* wv_raw = d_in[3];
    const void* wf_raw = d_in[4];
    const void* gw_raw = d_in[5];
    const void* wo_raw = d_in[6];

    char* base = (char*)d_ws;
    int* flag = (int*)base;
    float* fb = (float*)(base + 256);
    const size_t NB = (size_t)NROWS * 1024;   // floats per big buffer
    float* Q  = fb;
    float* K  = fb + NB;
    float* V  = fb + 2 * NB;
    float* GK = fb + 3 * NB;
    float* OK = fb + 4 * NB;
    u16* Wb  = (u16*)(fb + 5 * NB);           // 5 x 1,048,576 bf16 weights
    u16* WQb = Wb;
    u16* WKb = Wb + 1048576;
    u16* WVb = Wb + 2 * 1048576;
    u16* WFb = Wb + 3 * 1048576;
    u16* WOb = Wb + 4 * 1048576;
    u16* HSb = (u16*)OK;   // staged bf16 hidden lives in OK's dead window
    float* OV = Q;         // q dead after pass1
    u16* AN   = (u16*)K;   // k dead after pass1
    float* FO = V;         // v dead after pass2

    gsa_detect<<<1, 1, 0, stream>>>((const unsigned*)gw_raw, flag);
    gsa_tobf16<<<2048, 256, 0, stream>>>(hs_raw, HSb, 524288, flag);
    gsa_tobf16<<<512, 256, 0, stream>>>(wq_raw, WQb, 131072, flag);
    gsa_tobf16<<<512, 256, 0, stream>>>(wk_raw, WKb, 131072, flag);
    gsa_tobf16<<<512, 256, 0, stream>>>(wv_raw, WVb, 131072, flag);
    gsa_tobf16<<<512, 256, 0, stream>>>(wf_raw, WFb, 131072, flag);
    gsa_tobf16<<<512, 256, 0, stream>>>(wo_raw, WOb, 131072, flag);

    // fused QKVF: grid.x = 4 projections x 8 ntiles; acts {silu,silu,silu,gate}
    gsa_gemm_mfma<<<dim3(32, 32), 256, 0, stream>>>(HSb, WQb, WKb, WVb, WFb,
                                                    Q, K, V, GK, 0x01000000);
    gsa_pass1<<<512, 256, 0, stream>>>(Q, K, GK, OK);
    gsa_softmax<<<4096, 256, 0, stream>>>(OK);
    gsa_pass2<<<512, 256, 0, stream>>>(OK, V, GK, OV);
    gsa_rmsnorm<<<4096, 256, 0, stream>>>(OV, gw_raw, flag, AN);
    // Wo: grid.x = 8 -> sel always 0; act none
    gsa_gemm_mfma<<<dim3(8, 32), 256, 0, stream>>>(AN, WOb, WOb, WOb, WOb,
                                                   FO, FO, FO, FO, 0x02020202);
    gsa_emit<<<4096, 256, 0, stream>>>(FO, d_out, 1048576, flag);
}

// Round 6
// 1018.253 us; speedup vs baseline: 2.0512x; 1.0106x over previous
//
#include <hip/hip_runtime.h>
#include <math.h>

// Gated Slot Attention forward, MI355X round 5.
// B=2, T=2048, D=1024, H=4, DK=DV=M=256.
// NEW: pass1 as chunked scan (C=32) on MFMA: A=QK^T (mfma, K=256),
// intra=A@U in fp32 VALU (numerics), inter=Q@S0 (mfma, bf16 state via LDS),
// state hop = mfma(W~^T, K^T) accumulating into fp32 register state.
// pass2 still the R4 register-pipelined scalar scan.
#define TLEN 2048
#define NROWS 4096   // B*T

typedef unsigned short u16;
typedef __attribute__((ext_vector_type(8))) short bf16x8;
typedef __attribute__((ext_vector_type(4))) float f32x4;

// ---------------- dtype helpers ----------------
__device__ __forceinline__ float bf2f(u16 u) {
    unsigned v = ((unsigned)u) << 16; float f; __builtin_memcpy(&f, &v, 4); return f;
}
__device__ __forceinline__ u16 f2bf(float x) {
    unsigned u; __builtin_memcpy(&u, &x, 4);
    u += 0x7FFFu + ((u >> 16) & 1u);            // round-to-nearest-even
    return (u16)(u >> 16);
}
__device__ __forceinline__ float siluf(float x) { return x / (1.f + expf(-x)); }

template<int CTRL, int RM>
__device__ __forceinline__ float dpp_add(float x) {
    int t = __builtin_amdgcn_update_dpp(0, __builtin_bit_cast(int, x), CTRL, RM, 0xf, true);
    return x + __builtin_bit_cast(float, t);
}
__device__ __forceinline__ float wave_red_add(float x) {
    x = dpp_add<0x111, 0xf>(x);   // row_shr:1
    x = dpp_add<0x112, 0xf>(x);   // row_shr:2
    x = dpp_add<0x114, 0xf>(x);   // row_shr:4
    x = dpp_add<0x118, 0xf>(x);   // row_shr:8
    x = dpp_add<0x142, 0xa>(x);   // row_bcast:15
    x = dpp_add<0x143, 0xc>(x);   // row_bcast:31 -> lane 63 total
    return x;
}
__device__ __forceinline__ float readlane_f(float v, int l) {
    return __builtin_bit_cast(float, __builtin_amdgcn_readlane(__builtin_bit_cast(int, v), l));
}

// g_w is exactly ones(1024): first word 0x3F800000 (fp32) vs 0x3F803F80 (bf16x2).
__global__ void gsa_detect(const unsigned* __restrict__ gw, int* __restrict__ flag) {
    *flag = (gw[0] == 0x3F803F80u) ? 1 : 0;
}

__global__ __launch_bounds__(256) void gsa_tobf16(const void* __restrict__ src,
        u16* __restrict__ dst, int n8, const int* __restrict__ flag) {
    int i = blockIdx.x * 256 + threadIdx.x;
    if (i >= n8) return;
    if (*flag) {
        ((uint4*)dst)[i] = ((const uint4*)src)[i];
    } else {
        float4 a = ((const float4*)src)[2 * i];
        float4 b = ((const float4*)src)[2 * i + 1];
        uint4 o;
        o.x = (unsigned)f2bf(a.x) | ((unsigned)f2bf(a.y) << 16);
        o.y = (unsigned)f2bf(a.z) | ((unsigned)f2bf(a.w) << 16);
        o.z = (unsigned)f2bf(b.x) | ((unsigned)f2bf(b.y) << 16);
        o.w = (unsigned)f2bf(b.z) | ((unsigned)f2bf(b.w) << 16);
        ((uint4*)dst)[i] = o;
    }
}

__global__ __launch_bounds__(256) void gsa_emit(const float* __restrict__ src,
        void* __restrict__ dst, int n4, const int* __restrict__ flag) {
    int i = blockIdx.x * 256 + threadIdx.x;
    if (i >= n4) return;
    float4 v = ((const float4*)src)[i];
    if (*flag) {
        uint2 u;
        u.x = (unsigned)f2bf(v.x) | ((unsigned)f2bf(v.y) << 16);
        u.y = (unsigned)f2bf(v.z) | ((unsigned)f2bf(v.w) << 16);
        ((uint2*)dst)[i] = u;
    } else {
        ((float4*)dst)[i] = v;
    }
}

// ---------------- MFMA GEMM (projections) ----------------
#define GLOAD_LDS16(g, l) \
    __builtin_amdgcn_global_load_lds((const __attribute__((address_space(1))) void*)(g), \
                                     (__attribute__((address_space(3))) void*)(l), 16, 0, 0)

__global__ __launch_bounds__(256) void gsa_gemm_mfma(const u16* __restrict__ A,
        const u16* __restrict__ W0, const u16* __restrict__ W1,
        const u16* __restrict__ W2, const u16* __restrict__ W3,
        float* __restrict__ O0, float* __restrict__ O1,
        float* __restrict__ O2, float* __restrict__ O3, int actpack) {
    __shared__ u16 As[128 * 32];
    __shared__ u16 Bs[128 * 32];
    int tid = threadIdx.x;
    int sel = blockIdx.x >> 3;
    int ntile = blockIdx.x & 7;
    int mtile = blockIdx.y;
    const u16* W = (sel == 0) ? W0 : (sel == 1) ? W1 : (sel == 2) ? W2 : W3;
    float* Out   = (sel == 0) ? O0 : (sel == 1) ? O1 : (sel == 2) ? O2 : O3;
    int act = (actpack >> (sel * 8)) & 0xff;
    int w = tid >> 6, lane = tid & 63;
    int wm = w >> 1, wn = w & 1;
    int m0 = wm * 64, n0 = wn * 64;
    int srow = w * 32 + (lane >> 2);
    int scol = (lane & 3) * 8;
    const u16* Abase = A + (size_t)(mtile * 128 + srow) * 1024 + scol;
    const u16* Wbase = W + (size_t)(ntile * 128 + srow) * 1024 + scol;
    u16* AsDst0 = &As[(w * 32) * 32];
    u16* BsDst0 = &Bs[(w * 32) * 32];
    f32x4 acc[4][4];
    #pragma unroll
    for (int i = 0; i < 4; i++)
        #pragma unroll
        for (int j = 0; j < 4; j++) acc[i][j] = (f32x4){0.f, 0.f, 0.f, 0.f};
    int frow = lane & 15, fq = lane >> 4;
    for (int k0 = 0; k0 < 1024; k0 += 32) {
        __syncthreads();
        GLOAD_LDS16(Abase + k0, AsDst0);
        GLOAD_LDS16(Abase + k0 + (size_t)16 * 1024, AsDst0 + 16 * 32);
        GLOAD_LDS16(Wbase + k0, BsDst0);
        GLOAD_LDS16(Wbase + k0 + (size_t)16 * 1024, BsDst0 + 16 * 32);
        __syncthreads();
        bf16x8 af[4], bfv[4];
        #pragma unroll
        for (int mt = 0; mt < 4; mt++)
            af[mt] = *(const bf16x8*)&As[(m0 + mt * 16 + frow) * 32 + fq * 8];
        #pragma unroll
        for (int nt = 0; nt < 4; nt++)
            bfv[nt] = *(const bf16x8*)&Bs[(n0 + nt * 16 + frow) * 32 + fq * 8];
        #pragma unroll
        for (int mt = 0; mt < 4; mt++)
            #pragma unroll
            for (int nt = 0; nt < 4; nt++)
                acc[mt][nt] = __builtin_amdgcn_mfma_f32_16x16x32_bf16(
                    af[mt], bfv[nt], acc[mt][nt], 0, 0, 0);
    }
    #pragma unroll
    for (int mt = 0; mt < 4; mt++) {
        #pragma unroll
        for (int nt = 0; nt < 4; nt++) {
            #pragma unroll
            for (int r = 0; r < 4; r++) {
                float x = acc[mt][nt][r];
                int grow = mtile * 128 + m0 + mt * 16 + fq * 4 + r;
                int gcol = ntile * 128 + n0 + nt * 16 + frow;
                float val;
                if (act == 0) val = siluf(x);
                else if (act == 1) {
                    float ls = (x >= 0.f) ? -log1pf(expf(-x)) : (x - log1pf(expf(x)));
                    val = expf(0.125f * ls);   // gk = sigmoid(x)^(1/8)
                } else val = x;
                Out[(size_t)grow * 1024 + gcol] = val;
            }
        }
    }
}

// ---------------- Pass 1: chunked MFMA scan ----------------
// One WG per (b,h, 32-slot group). 256 thr = 4 waves. C=32 chunk.
// ok_t[m] = E_t[m]*( q_t.S0[:,m] + sum_{tau<=t} A[t,tau]*U[tau,m] )
// S'[m,k] = EC[m]*S[m,k] + sum_tau Wt[m,tau]*K[tau,k]   (state in fp32 regs)
#define P1C 32
#define QS_STR 264   // u16; 528B rows (16B-aligned, 2-way max bank alias)
#define KT_STR 32    // u16
#define WT_STR 40    // u16
#define A_STR  33    // f32
#define F_STR  36    // f32 (float4-aligned rows)

__global__ __launch_bounds__(256) void gsa_pass1_chunk(
        const float* __restrict__ q, const float* __restrict__ k,
        const float* __restrict__ gk, float* __restrict__ ok) {
    __shared__ __align__(16) u16 Qs[P1C * QS_STR];
    __shared__ __align__(16) u16 Ks[P1C * QS_STR];
    __shared__ __align__(16) u16 Kt[256 * KT_STR];
    __shared__ __align__(16) u16 St[32 * QS_STR];
    __shared__ __align__(16) u16 Wt[32 * WT_STR];
    __shared__ __align__(16) float A_l[P1C * A_STR];
    __shared__ __align__(16) float gs[P1C * F_STR];
    __shared__ __align__(16) float fs[P1C * F_STR];
    __shared__ __align__(16) float E_l[P1C * F_STR];
    __shared__ __align__(16) float U_l[P1C * F_STR];
    __shared__ __align__(16) float P_l[P1C * F_STR];
    __shared__ float ECm[32];

    int tid = threadIdx.x;
    int bh = blockIdx.x & 7;
    int mg = blockIdx.x >> 3;            // 0..7 slot group
    int b = bh >> 2, h = bh & 3;
    int w = tid >> 6, lane = tid & 63;
    int frow = lane & 15, fq = lane >> 4;
    size_t basebh = ((size_t)b * TLEN) * 1024 + h * 256;
    const float* qb = q + basebh;
    const float* kb = k + basebh;
    const float* gb = gk + basebh + mg * 32;
    float* okb = ok + basebh + mg * 32;

    int tt = w >> 1;            // t-tile for A and G GEMMs
    int tu = w & 1;             // tau-tile (A) / m-tile (G)
    int mtile = w & 1, khalf = w >> 1;   // update-GEMM role

    f32x4 acc[8];               // state S[m][k]: m-tile=mtile, k-tiles khalf*8..+8
    #pragma unroll
    for (int i = 0; i < 8; i++) acc[i] = (f32x4){0.f, 0.f, 0.f, 0.f};
    for (int i = tid; i < 32 * QS_STR; i += 256) St[i] = 0;
    __syncthreads();

    for (int c = 0; c < TLEN / P1C; ++c) {
        int t0c = c * P1C;
        // ---- stage Q,K chunk (fp32->bf16), K transposed, g and f=log(g) ----
        #pragma unroll
        for (int j = 0; j < 8; ++j) {
            int idx4 = tid * 8 + j;            // 2048 float4 per matrix
            int t = idx4 >> 6;
            int k4 = (idx4 & 63) * 4;
            float4 qv = *(const float4*)(qb + (size_t)(t0c + t) * 1024 + k4);
            float4 kv = *(const float4*)(kb + (size_t)(t0c + t) * 1024 + k4);
            u16* qd = &Qs[t * QS_STR + k4];
            qd[0] = f2bf(qv.x); qd[1] = f2bf(qv.y);
            qd[2] = f2bf(qv.z); qd[3] = f2bf(qv.w);
            u16 c0 = f2bf(kv.x), c1 = f2bf(kv.y), c2 = f2bf(kv.z), c3 = f2bf(kv.w);
            u16* kd = &Ks[t * QS_STR + k4];
            kd[0] = c0; kd[1] = c1; kd[2] = c2; kd[3] = c3;
            Kt[(k4 + 0) * KT_STR + t] = c0; Kt[(k4 + 1) * KT_STR + t] = c1;
            Kt[(k4 + 2) * KT_STR + t] = c2; Kt[(k4 + 3) * KT_STR + t] = c3;
        }
        {
            int t = tid >> 3, m4 = (tid & 7) * 4;
            float4 gv = *(const float4*)(gb + (size_t)(t0c + t) * 1024 + m4);
            *(float4*)&gs[t * F_STR + m4] = gv;
            float4 fv;
            fv.x = __logf(gv.x); fv.y = __logf(gv.y);
            fv.z = __logf(gv.z); fv.w = __logf(gv.w);
            *(float4*)&fs[t * F_STR + m4] = fv;
        }
        __syncthreads();   // B0
        // ---- in-chunk decay scan (wave 0, lanes 0..31; register-resident) ----
        if (w == 0 && lane < 32) {
            float fv[P1C], gv[P1C];
            #pragma unroll
            for (int t = 0; t < P1C; ++t) {
                fv[t] = fs[t * F_STR + lane];
                gv[t] = gs[t * F_STR + lane];
            }
            float phi = 0.f, E = 1.f;
            #pragma unroll
            for (int t = 0; t < P1C; ++t) {
                phi += fv[t];
                E = __expf(phi);
                E_l[t * F_STR + lane] = E;
                float u = (1.f - gv[t]) * __expf(-phi);
                U_l[t * F_STR + lane] = u;
                fv[t] = u;                     // reuse for Wt
            }
            ECm[lane] = E;
            #pragma unroll
            for (int t = 0; t < P1C; ++t)
                Wt[lane * WT_STR + t] = f2bf(fv[t] * E);   // (EC/Et)*s in [0,1]
        }
        __syncthreads();   // B1
        // ---- A = Q K^T (tile tt,tu) and G = Q S0^T (tile tt, m-tile tu) ----
        f32x4 aacc = (f32x4){0.f, 0.f, 0.f, 0.f};
        f32x4 gacc = (f32x4){0.f, 0.f, 0.f, 0.f};
        #pragma unroll
        for (int k0 = 0; k0 < 8; ++k0) {
            bf16x8 af = *(const bf16x8*)&Qs[(tt * 16 + frow) * QS_STR + k0 * 32 + fq * 8];
            bf16x8 bk = *(const bf16x8*)&Ks[(tu * 16 + frow) * QS_STR + k0 * 32 + fq * 8];
            bf16x8 bs = *(const bf16x8*)&St[(tu * 16 + frow) * QS_STR + k0 * 32 + fq * 8];
            aacc = __builtin_amdgcn_mfma_f32_16x16x32_bf16(af, bk, aacc, 0, 0, 0);
            gacc = __builtin_amdgcn_mfma_f32_16x16x32_bf16(af, bs, gacc, 0, 0, 0);
        }
        // masked A -> LDS (D layout: row t = fq*4+r, col tau = frow)
        #pragma unroll
        for (int r = 0; r < 4; ++r) {
            int t = tt * 16 + fq * 4 + r, tau = tu * 16 + frow;
            A_l[t * A_STR + tau] = (tau <= t) ? aacc[r] : 0.f;
        }
        // ---- state scale + update: acc = EC*acc + Wt^T @ Kt ----
        float esc[4];
        #pragma unroll
        for (int r = 0; r < 4; ++r) esc[r] = ECm[mtile * 16 + fq * 4 + r];
        bf16x8 wtf = *(const bf16x8*)&Wt[(mtile * 16 + frow) * WT_STR + fq * 8];
        #pragma unroll
        for (int kk = 0; kk < 8; ++kk) {
            #pragma unroll
            for (int r = 0; r < 4; ++r) acc[kk][r] *= esc[r];
            bf16x8 ktf = *(const bf16x8*)&Kt[((khalf * 8 + kk) * 16 + frow) * KT_STR + fq * 8];
            acc[kk] = __builtin_amdgcn_mfma_f32_16x16x32_bf16(wtf, ktf, acc[kk], 0, 0, 0);
        }
        __syncthreads();   // B2: A_l complete; all St reads (G) done
        // ---- new St (bf16) for next chunk's G ----
        #pragma unroll
        for (int kk = 0; kk < 8; ++kk)
            #pragma unroll
            for (int r = 0; r < 4; ++r)
                St[(mtile * 16 + fq * 4 + r) * QS_STR + (khalf * 8 + kk) * 16 + frow]
                    = f2bf(acc[kk][r]);
        // ---- intra P = A_masked @ U in fp32 VALU ----
        {
            int t = tid & 31, mgr = tid >> 5;
            float4 p = {0.f, 0.f, 0.f, 0.f};
            #pragma unroll 8
            for (int tau = 0; tau < P1C; ++tau) {
                float a = A_l[t * A_STR + tau];
                float4 u4 = *(const float4*)&U_l[tau * F_STR + mgr * 4];
                p.x = fmaf(a, u4.x, p.x); p.y = fmaf(a, u4.y, p.y);
                p.z = fmaf(a, u4.z, p.z); p.w = fmaf(a, u4.w, p.w);
            }
            *(float4*)&P_l[t * F_STR + mgr * 4] = p;
        }
        __syncthreads();   // B3
        // ---- ok = E * (G + P) ----
        #pragma unroll
        for (int r = 0; r < 4; ++r) {
            int t = tt * 16 + fq * 4 + r, m = tu * 16 + frow;
            float val = E_l[t * F_STR + m] * (gacc[r] + P_l[t * F_STR + m]);
            okb[(size_t)(t0c + t) * 1024 + m] = val;
        }
        // next B0 orders these reads vs next chunk's E/P writes
    }
}

// ---------------- softmax over M=256, in place ----------------
__global__ __launch_bounds__(256) void gsa_softmax(float* __restrict__ x) {
    int row = blockIdx.x * 4 + (threadIdx.x >> 6);
    int lane = threadIdx.x & 63;
    float* p = x + (size_t)row * 256 + lane * 4;
    float4 v = *(float4*)p;
    float mx = fmaxf(fmaxf(v.x, v.y), fmaxf(v.z, v.w));
    #pragma unroll
    for (int off = 32; off; off >>= 1) mx = fmaxf(mx, __shfl_xor(mx, off));
    v.x = expf(v.x - mx); v.y = expf(v.y - mx);
    v.z = expf(v.z - mx); v.w = expf(v.w - mx);
    float sm = v.x + v.y + v.z + v.w;
    #pragma unroll
    for (int off = 32; off; off >>= 1) sm += __shfl_xor(sm, off);
    float inv = 1.f / sm;
    v.x *= inv; v.y *= inv; v.z *= inv; v.w *= inv;
    *(float4*)p = v;
}

// ---------------- Pass 2 (R4 register-pipelined) ----------------
__device__ __forceinline__ void p2_load(const float* __restrict__ qb,
        const float* __restrict__ gb, const float* __restrict__ vbc,
        int t0, int lane, float4* av, float4* gv, float& vs) {
    #pragma unroll
    for (int i = 0; i < 8; i++) {
        av[i] = *(const float4*)(qb + (size_t)(t0 + i) * 1024 + lane * 4);
        gv[i] = *(const float4*)(gb + (size_t)(t0 + i) * 1024 + lane * 4);
    }
    vs = vbc[(size_t)(t0 + (lane & 7)) * 1024];
}
__device__ __forceinline__ void p2_comp(const float4* av, const float4* gv,
        float vs, float4& S, float* __restrict__ ob, int t0, int lane) {
    #pragma unroll
    for (int tt = 0; tt < 8; tt++) {
        float vvt = readlane_f(vs, tt);
        float4 g4 = gv[tt];
        float4 a4 = av[tt];
        S.x = fmaf(S.x, g4.x, (1.f - g4.x) * vvt);
        S.y = fmaf(S.y, g4.y, (1.f - g4.y) * vvt);
        S.z = fmaf(S.z, g4.z, (1.f - g4.z) * vvt);
        S.w = fmaf(S.w, g4.w, (1.f - g4.w) * vvt);
        float p = a4.x * S.x + a4.y * S.y + a4.z * S.z + a4.w * S.w;
        float r = wave_red_add(p);
        if (lane == 63) ob[(size_t)(t0 + tt) * 1024] = r;
    }
}
__global__ __launch_bounds__(256) void gsa_pass2(const float* __restrict__ qv,
        const float* __restrict__ v, const float* __restrict__ gk,
        float* __restrict__ ov) {
    int tid = threadIdx.x;
    int bh = blockIdx.x & 7;
    int vtile = blockIdx.x >> 3;
    int b = bh >> 2, h = bh & 3;
    int wave = tid >> 6, lane = tid & 63;
    int vcol = vtile * 4 + wave;
    size_t rb = (size_t)b * TLEN;
    const float* qb = qv + rb * 1024 + h * 256;
    const float* gb = gk + rb * 1024 + h * 256;
    const float* vbc = v + rb * 1024 + h * 256 + vcol;
    float* ob = ov + rb * 1024 + h * 256 + vcol;
    float4 S = make_float4(0.f, 0.f, 0.f, 0.f);
    float4 aa[8], ga4[8]; float va;
    p2_load(qb, gb, vbc, 0, lane, aa, ga4, va);
    for (int t0 = 0; t0 < TLEN; t0 += 16) {
        float4 an[8], gn4[8]; float vn;
        p2_load(qb, gb, vbc, t0 + 8, lane, an, gn4, vn);
        p2_comp(aa, ga4, va, S, ob, t0, lane);
        if (t0 + 16 < TLEN) p2_load(qb, gb, vbc, t0 + 16, lane, aa, ga4, va);
        p2_comp(an, gn4, vn, S, ob, t0 + 8, lane);
    }
}

// ---------------- silu -> RMSNorm(1024) -> *g_w -> bf16 ----------------
__global__ __launch_bounds__(256) void gsa_rmsnorm(const float* __restrict__ ov,
        const void* __restrict__ gw, const int* __restrict__ flag,
        u16* __restrict__ out) {
    __shared__ float part[4];
    int row = blockIdx.x;
    int tid = threadIdx.x;
    const float* p = ov + (size_t)row * 1024 + tid * 4;
    float4 x = *(const float4*)p;
    float y0 = siluf(x.x), y1 = siluf(x.y), y2 = siluf(x.z), y3 = siluf(x.w);
    float ssum = y0 * y0 + y1 * y1 + y2 * y2 + y3 * y3;
    #pragma unroll
    for (int off = 32; off; off >>= 1) ssum += __shfl_xor(ssum, off);
    if ((tid & 63) == 0) part[tid >> 6] = ssum;
    __syncthreads();
    float tot = part[0] + part[1] + part[2] + part[3];
    float r = rsqrtf(tot * (1.f / 1024.f) + 1e-5f);
    float4 g;
    if (*flag) {
        ushort4 u = ((const ushort4*)gw)[tid];
        g.x = bf2f(u.x); g.y = bf2f(u.y); g.z = bf2f(u.z); g.w = bf2f(u.w);
    } else {
        g = ((const float4*)gw)[tid];
    }
    ushort4 o;
    o.x = f2bf(y0 * r * g.x); o.y = f2bf(y1 * r * g.y);
    o.z = f2bf(y2 * r * g.z); o.w = f2bf(y3 * r * g.w);
    ((ushort4*)(out + (size_t)row * 1024))[tid] = o;
}

// ---------------- launcher ----------------
extern "C" void kernel_launch(void* const* d_in, const int* in_sizes, int n_in,
                              void* d_out, int out_size, void* d_ws, size_t ws_size,
                              hipStream_t stream) {
    (void)in_sizes; (void)n_in; (void)out_size; (void)ws_size;
    const void* hs_raw = d_in[0];
    const void* wq_raw = d_in[1];
    const void* wk_raw = d_in[2];
    const void* wv_raw = d_in[3];
    const void* wf_raw = d_in[4];
    const void* gw_raw = d_in[5];
    const void* wo_raw = d_in[6];

    char* base = (char*)d_ws;
    int* flag = (int*)base;
    float* fb = (float*)(base + 256);
    const size_t NB = (size_t)NROWS * 1024;
    float* Q  = fb;
    float* K  = fb + NB;
    float* V  = fb + 2 * NB;
    float* GK = fb + 3 * NB;
    float* OK = fb + 4 * NB;
    u16* Wb  = (u16*)(fb + 5 * NB);
    u16* WQb = Wb;
    u16* WKb = Wb + 1048576;
    u16* WVb = Wb + 2 * 1048576;
    u16* WFb = Wb + 3 * 1048576;
    u16* WOb = Wb + 4 * 1048576;
    u16* HSb = (u16*)OK;   // staged bf16 hidden in OK's dead window
    float* OV = Q;         // q dead after pass1
    u16* AN   = (u16*)K;   // k dead after pass1
    float* FO = V;         // v dead after pass2

    gsa_detect<<<1, 1, 0, stream>>>((const unsigned*)gw_raw, flag);
    gsa_tobf16<<<2048, 256, 0, stream>>>(hs_raw, HSb, 524288, flag);
    gsa_tobf16<<<512, 256, 0, stream>>>(wq_raw, WQb, 131072, flag);
    gsa_tobf16<<<512, 256, 0, stream>>>(wk_raw, WKb, 131072, flag);
    gsa_tobf16<<<512, 256, 0, stream>>>(wv_raw, WVb, 131072, flag);
    gsa_tobf16<<<512, 256, 0, stream>>>(wf_raw, WFb, 131072, flag);
    gsa_tobf16<<<512, 256, 0, stream>>>(wo_raw, WOb, 131072, flag);

    gsa_gemm_mfma<<<dim3(32, 32), 256, 0, stream>>>(HSb, WQb, WKb, WVb, WFb,
                                                    Q, K, V, GK, 0x01000000);
    gsa_pass1_chunk<<<64, 256, 0, stream>>>(Q, K, GK, OK);
    gsa_softmax<<<4096, 256, 0, stream>>>(OK);
    gsa_pass2<<<512, 256, 0, stream>>>(OK, V, GK, OV);
    gsa_rmsnorm<<<4096, 256, 0, stream>>>(OV, gw_raw, flag, AN);
    gsa_gemm_mfma<<<dim3(8, 32), 256, 0, stream>>>(AN, WOb, WOb, WOb, WOb,
                                                   FO, FO, FO, FO, 0x02020202);
    gsa_emit<<<4096, 256, 0, stream>>>(FO, d_out, 1048576, flag);
}

// Round 7
// 465.143 us; speedup vs baseline: 4.4903x; 2.1891x over previous
//
#include <hip/hip_runtime.h>
#include <math.h>

// Gated Slot Attention forward, MI355X round 6.
// B=2, T=2048, D=1024, H=4, DK=DV=M=256.
// R6: both recurrences as chunk-parallel 3-phase scans (C=64, Nc=32/bh):
//   A: per-chunk delta D (MFMA) + chunk decay EC  [256 WGs]
//   B: inter-chunk boundary scan, in-place        [512 WGs, streaming]
//   C: outputs ok/o = E*(Q@S0 + Amask@U)          [256 WGs, MFMA + fp32 VALU]
// R5's single-kernel chunk scan used only 64 WGs (75% idle) -> no win.
#define TLEN 2048
#define NROWS 4096   // B*T
#define CHK 64
#define NCHK 32      // chunks per (b,h)

typedef unsigned short u16;
typedef unsigned int u32;
typedef __attribute__((ext_vector_type(8))) short bf16x8;
typedef __attribute__((ext_vector_type(4))) float f32x4;

#define MFMA(a, b, c) __builtin_amdgcn_mfma_f32_16x16x32_bf16(a, b, c, 0, 0, 0)

// ---------------- dtype helpers ----------------
__device__ __forceinline__ float bf2f(u16 u) {
    u32 v = ((u32)u) << 16; float f; __builtin_memcpy(&f, &v, 4); return f;
}
__device__ __forceinline__ u16 f2bf(float x) {
    u32 u; __builtin_memcpy(&u, &x, 4);
    u += 0x7FFFu + ((u >> 16) & 1u);            // round-to-nearest-even
    return (u16)(u >> 16);
}
__device__ __forceinline__ u32 pack2bf(float a, float b) {
    return (u32)f2bf(a) | ((u32)f2bf(b) << 16);
}
__device__ __forceinline__ float bflo(u32 u) { return bf2f((u16)(u & 0xFFFFu)); }
__device__ __forceinline__ float bfhi(u32 u) { return bf2f((u16)(u >> 16)); }
__device__ __forceinline__ float siluf(float x) { return x / (1.f + expf(-x)); }

// g_w is exactly ones(1024): first word 0x3F800000 (fp32) vs 0x3F803F80 (bf16x2).
__global__ void gsa_detect(const u32* __restrict__ gw, int* __restrict__ flag) {
    *flag = (gw[0] == 0x3F803F80u) ? 1 : 0;
}

__global__ __launch_bounds__(256) void gsa_tobf16(const void* __restrict__ src,
        u16* __restrict__ dst, int n8, const int* __restrict__ flag) {
    int i = blockIdx.x * 256 + threadIdx.x;
    if (i >= n8) return;
    if (*flag) {
        ((uint4*)dst)[i] = ((const uint4*)src)[i];
    } else {
        float4 a = ((const float4*)src)[2 * i];
        float4 b = ((const float4*)src)[2 * i + 1];
        uint4 o;
        o.x = pack2bf(a.x, a.y); o.y = pack2bf(a.z, a.w);
        o.z = pack2bf(b.x, b.y); o.w = pack2bf(b.z, b.w);
        ((uint4*)dst)[i] = o;
    }
}

__global__ __launch_bounds__(256) void gsa_emit(const float* __restrict__ src,
        void* __restrict__ dst, int n4, const int* __restrict__ flag) {
    int i = blockIdx.x * 256 + threadIdx.x;
    if (i >= n4) return;
    float4 v = ((const float4*)src)[i];
    if (*flag) {
        uint2 u; u.x = pack2bf(v.x, v.y); u.y = pack2bf(v.z, v.w);
        ((uint2*)dst)[i] = u;
    } else {
        ((float4*)dst)[i] = v;
    }
}

// ---------------- MFMA GEMM (projections) ----------------
#define GLOAD_LDS16(g, l) \
    __builtin_amdgcn_global_load_lds((const __attribute__((address_space(1))) void*)(g), \
                                     (__attribute__((address_space(3))) void*)(l), 16, 0, 0)

__global__ __launch_bounds__(256) void gsa_gemm_mfma(const u16* __restrict__ A,
        const u16* __restrict__ W0, const u16* __restrict__ W1,
        const u16* __restrict__ W2, const u16* __restrict__ W3,
        void* __restrict__ O0, void* __restrict__ O1,
        void* __restrict__ O2, void* __restrict__ O3, int actpack, int obfmask) {
    __shared__ u16 As[128 * 32];
    __shared__ u16 Bs[128 * 32];
    int tid = threadIdx.x;
    int sel = blockIdx.x >> 3;
    int ntile = blockIdx.x & 7;
    int mtile = blockIdx.y;
    const u16* W = (sel == 0) ? W0 : (sel == 1) ? W1 : (sel == 2) ? W2 : W3;
    void* Out    = (sel == 0) ? O0 : (sel == 1) ? O1 : (sel == 2) ? O2 : O3;
    int act = (actpack >> (sel * 8)) & 0xff;
    int obf = (obfmask >> sel) & 1;
    int w = tid >> 6, lane = tid & 63;
    int wm = w >> 1, wn = w & 1;
    int m0 = wm * 64, n0 = wn * 64;
    int srow = w * 32 + (lane >> 2);
    int scol = (lane & 3) * 8;
    const u16* Abase = A + (size_t)(mtile * 128 + srow) * 1024 + scol;
    const u16* Wbase = W + (size_t)(ntile * 128 + srow) * 1024 + scol;
    u16* AsDst0 = &As[(w * 32) * 32];
    u16* BsDst0 = &Bs[(w * 32) * 32];
    f32x4 acc[4][4];
    #pragma unroll
    for (int i = 0; i < 4; i++)
        #pragma unroll
        for (int j = 0; j < 4; j++) acc[i][j] = (f32x4){0.f, 0.f, 0.f, 0.f};
    int frow = lane & 15, fq = lane >> 4;
    for (int k0 = 0; k0 < 1024; k0 += 32) {
        __syncthreads();
        GLOAD_LDS16(Abase + k0, AsDst0);
        GLOAD_LDS16(Abase + k0 + (size_t)16 * 1024, AsDst0 + 16 * 32);
        GLOAD_LDS16(Wbase + k0, BsDst0);
        GLOAD_LDS16(Wbase + k0 + (size_t)16 * 1024, BsDst0 + 16 * 32);
        __syncthreads();
        bf16x8 af[4], bfv[4];
        #pragma unroll
        for (int mt = 0; mt < 4; mt++)
            af[mt] = *(const bf16x8*)&As[(m0 + mt * 16 + frow) * 32 + fq * 8];
        #pragma unroll
        for (int nt = 0; nt < 4; nt++)
            bfv[nt] = *(const bf16x8*)&Bs[(n0 + nt * 16 + frow) * 32 + fq * 8];
        #pragma unroll
        for (int mt = 0; mt < 4; mt++)
            #pragma unroll
            for (int nt = 0; nt < 4; nt++)
                acc[mt][nt] = MFMA(af[mt], bfv[nt], acc[mt][nt]);
    }
    #pragma unroll
    for (int mt = 0; mt < 4; mt++) {
        #pragma unroll
        for (int nt = 0; nt < 4; nt++) {
            #pragma unroll
            for (int r = 0; r < 4; r++) {
                float x = acc[mt][nt][r];
                int grow = mtile * 128 + m0 + mt * 16 + fq * 4 + r;
                int gcol = ntile * 128 + n0 + nt * 16 + frow;
                float val;
                if (act == 0) val = siluf(x);
                else if (act == 1) {
                    float ls = (x >= 0.f) ? -log1pf(expf(-x)) : (x - log1pf(expf(x)));
                    val = expf(0.125f * ls);   // gk = sigmoid(x)^(1/8)
                } else val = x;
                size_t o = (size_t)grow * 1024 + gcol;
                if (obf) ((u16*)Out)[o] = f2bf(val);
                else     ((float*)Out)[o] = val;
            }
        }
    }
}

// ---------------- Phase A: per-chunk local state delta ----------------
// P==1 (pass1): D[m,k] = sum_tau W[tau,m] K[tau,k]; writes EC.
// P==2 (pass2): D[v,m] = sum_tau V[tau,v] W[tau,m].
// W[tau,m] = (1-g_tau[m]) * exp(phiC - phi_tau)  in [0,1].
template<int P>
__global__ __launch_bounds__(256) void gsa_p_local(const u16* __restrict__ Xb,
        const float* __restrict__ GKp, u16* __restrict__ Sb, float* __restrict__ ECb) {
    __shared__ u16 Xt[256 * 72];   // X^T [x][tau]
    __shared__ u16 Wt[256 * 72];   // W^T [m][tau]
    int tid = threadIdx.x;
    int bh = blockIdx.x & 7, c = blockIdx.x >> 3;
    int b = bh >> 2, h = bh & 3, t0 = c * CHK;
    size_t gbase = ((size_t)(b * TLEN + t0)) * 1024 + h * 256;
    // stage X^T: thread owns column x=tid, loops tau (coalesced u16 loads)
    {
        const u16* xp = Xb + gbase + tid;
        #pragma unroll
        for (int t8 = 0; t8 < 8; t8++) {
            bf16x8 v;
            #pragma unroll
            for (int j = 0; j < 8; j++) v[j] = (short)xp[(size_t)(t8 * 8 + j) * 1024];
            *(bf16x8*)&Xt[tid * 72 + t8 * 8] = v;
        }
    }
    // decay scan: thread owns m=tid
    {
        float g[CHK], f[CHK];
        const float* gp = GKp + gbase + tid;
        #pragma unroll
        for (int t = 0; t < CHK; t++) g[t] = gp[(size_t)t * 1024];
        float phiC = 0.f;
        #pragma unroll
        for (int t = 0; t < CHK; t++) { f[t] = __logf(g[t]); phiC += f[t]; }
        if (P == 1) ECb[(bh * NCHK + c) * 256 + tid] = __expf(phiC);
        float phi = 0.f;
        #pragma unroll
        for (int t8 = 0; t8 < 8; t8++) {
            bf16x8 v;
            #pragma unroll
            for (int j = 0; j < 8; j++) {
                phi += f[t8 * 8 + j];
                v[j] = (short)f2bf((1.f - g[t8 * 8 + j]) * __expf(phiC - phi));
            }
            *(bf16x8*)&Wt[tid * 72 + t8 * 8] = v;
        }
    }
    __syncthreads();
    // MFMA: out rows from A-op, cols from B-op; K=64 (2 mfma steps)
    int w = tid >> 6, lane = tid & 63, frow = lane & 15, fq = lane >> 4;
    const u16* Arows = (P == 1) ? Wt : Xt;
    const u16* Brows = (P == 1) ? Xt : Wt;
    bf16x8 afr[4][2];
    #pragma unroll
    for (int it = 0; it < 4; it++)
        #pragma unroll
        for (int ks = 0; ks < 2; ks++)
            afr[it][ks] = *(const bf16x8*)&Arows[(w * 64 + it * 16 + frow) * 72 + ks * 32 + fq * 8];
    u16* Sp = Sb + (size_t)(bh * NCHK + c) * 65536;
    for (int jt = 0; jt < 16; jt++) {
        f32x4 ac[4];
        #pragma unroll
        for (int it = 0; it < 4; it++) ac[it] = (f32x4){0.f, 0.f, 0.f, 0.f};
        #pragma unroll
        for (int ks = 0; ks < 2; ks++) {
            bf16x8 bfr = *(const bf16x8*)&Brows[(jt * 16 + frow) * 72 + ks * 32 + fq * 8];
            #pragma unroll
            for (int it = 0; it < 4; it++) ac[it] = MFMA(afr[it][ks], bfr, ac[it]);
        }
        #pragma unroll
        for (int it = 0; it < 4; it++)
            #pragma unroll
            for (int r = 0; r < 4; r++)
                Sp[(size_t)(w * 64 + it * 16 + fq * 4 + r) * 256 + jt * 16 + frow]
                    = f2bf(ac[it][r]);
    }
}

// ---------------- Phase B: inter-chunk boundary scan (in place) ----------------
// pass1: elements (m, k..k+3): EC scalar per thread.
__global__ __launch_bounds__(256) void gsa_scan1(u16* __restrict__ Sb,
        const float* __restrict__ ECb) {
    int bh = blockIdx.x & 7, part = blockIdx.x >> 3;
    int lin = part * 1024 + threadIdx.x * 4;
    int m = lin >> 8, k = lin & 255;
    u16* Sp = Sb + (size_t)bh * NCHK * 65536 + m * 256 + k;
    const float* Ep = ECb + bh * NCHK * 256 + m;
    float s0 = 0.f, s1 = 0.f, s2 = 0.f, s3 = 0.f;
    for (int c = 0; c < NCHK; c++) {
        uint2 d = *(uint2*)(Sp + (size_t)c * 65536);
        float ec = Ep[c * 256];
        uint2 o; o.x = pack2bf(s0, s1); o.y = pack2bf(s2, s3);
        *(uint2*)(Sp + (size_t)c * 65536) = o;          // S0_c (state at chunk start)
        s0 = fmaf(ec, s0, bflo(d.x)); s1 = fmaf(ec, s1, bfhi(d.x));
        s2 = fmaf(ec, s2, bflo(d.y)); s3 = fmaf(ec, s3, bfhi(d.y));
    }
}
// pass2: elements (v, m..m+3): EC varies within the 4 -> float4.
__global__ __launch_bounds__(256) void gsa_scan2(u16* __restrict__ Sb,
        const float* __restrict__ ECb) {
    int bh = blockIdx.x & 7, part = blockIdx.x >> 3;
    int lin = part * 1024 + threadIdx.x * 4;
    int v = lin >> 8, m = lin & 255;
    u16* Sp = Sb + (size_t)bh * NCHK * 65536 + v * 256 + m;
    const float* Ep = ECb + bh * NCHK * 256 + m;
    float s0 = 0.f, s1 = 0.f, s2 = 0.f, s3 = 0.f;
    for (int c = 0; c < NCHK; c++) {
        uint2 d = *(uint2*)(Sp + (size_t)c * 65536);
        float4 e = *(const float4*)(Ep + c * 256);
        uint2 o; o.x = pack2bf(s0, s1); o.y = pack2bf(s2, s3);
        *(uint2*)(Sp + (size_t)c * 65536) = o;
        s0 = fmaf(e.x, s0, bflo(d.x)); s1 = fmaf(e.y, s1, bfhi(d.x));
        s2 = fmaf(e.z, s2, bflo(d.y)); s3 = fmaf(e.w, s3, bfhi(d.y));
    }
}

// ---------------- Phase C pass1: ok = E * (Q@S0^T + Amask@U) ----------------
__global__ __launch_bounds__(256) void gsa_p1_out(const u16* __restrict__ Qb,
        const u16* __restrict__ Kb, const float* __restrict__ GKp,
        const u16* __restrict__ Sb, float* __restrict__ OK) {
    __shared__ u16 Qs[64 * 264];
    __shared__ float Asc[64 * 68];
    __shared__ float Gs[64 * 260];
    int tid = threadIdx.x;
    int bh = blockIdx.x & 7, c = blockIdx.x >> 3;
    int b = bh >> 2, h = bh & 3, t0 = c * CHK;
    size_t gbase = ((size_t)(b * TLEN + t0)) * 1024 + h * 256;
    // stage Q chunk
    #pragma unroll
    for (int j = 0; j < 8; j++) {
        int lin = j * 256 + tid;
        int t = lin >> 5, kg = (lin & 31) * 8;
        *(bf16x8*)&Qs[t * 264 + kg] = *(const bf16x8*)(Qb + gbase + (size_t)t * 1024 + kg);
    }
    __syncthreads();
    int w = tid >> 6, lane = tid & 63, frow = lane & 15, fq = lane >> 4;
    // A = Q K^T for t-tile w (B-op direct from global, L2-resident)
    {
        const u16* Kg = Kb + gbase;
        #pragma unroll
        for (int tt = 0; tt < 4; tt++) {
            f32x4 ac = (f32x4){0.f, 0.f, 0.f, 0.f};
            #pragma unroll
            for (int ks = 0; ks < 8; ks++) {
                bf16x8 a = *(const bf16x8*)&Qs[(w * 16 + frow) * 264 + ks * 32 + fq * 8];
                bf16x8 bb = *(const bf16x8*)(Kg + (size_t)(tt * 16 + frow) * 1024 + ks * 32 + fq * 8);
                ac = MFMA(a, bb, ac);
            }
            #pragma unroll
            for (int r = 0; r < 4; r++) {
                int t = w * 16 + fq * 4 + r, tau = tt * 16 + frow;
                Asc[t * 68 + tau] = (tau <= t) ? ac[r] : 0.f;
            }
        }
    }
    // G = Q @ S0 for m-range w*64 (S0[m][k] bf16, direct global B-op)
    {
        const u16* Sg = Sb + (size_t)(bh * NCHK + c) * 65536;
        f32x4 gac[4][4];
        #pragma unroll
        for (int tt = 0; tt < 4; tt++)
            #pragma unroll
            for (int mt = 0; mt < 4; mt++) gac[tt][mt] = (f32x4){0.f, 0.f, 0.f, 0.f};
        for (int ks = 0; ks < 8; ks++) {
            bf16x8 bfr[4], afr[4];
            #pragma unroll
            for (int mt = 0; mt < 4; mt++)
                bfr[mt] = *(const bf16x8*)(Sg + (size_t)(w * 64 + mt * 16 + frow) * 256 + ks * 32 + fq * 8);
            #pragma unroll
            for (int tt = 0; tt < 4; tt++)
                afr[tt] = *(const bf16x8*)&Qs[(tt * 16 + frow) * 264 + ks * 32 + fq * 8];
            #pragma unroll
            for (int tt = 0; tt < 4; tt++)
                #pragma unroll
                for (int mt = 0; mt < 4; mt++)
                    gac[tt][mt] = MFMA(afr[tt], bfr[mt], gac[tt][mt]);
        }
        #pragma unroll
        for (int tt = 0; tt < 4; tt++)
            #pragma unroll
            for (int mt = 0; mt < 4; mt++)
                #pragma unroll
                for (int r = 0; r < 4; r++)
                    Gs[(tt * 16 + fq * 4 + r) * 260 + w * 64 + mt * 16 + frow] = gac[tt][mt][r];
    }
    __syncthreads();
    // scan (per m=tid) + epilogue (fp32 intra, A broadcast reads)
    float E[CHK], U[CHK];
    {
        float g[CHK];
        const float* gp = GKp + gbase + tid;
        #pragma unroll
        for (int t = 0; t < CHK; t++) g[t] = gp[(size_t)t * 1024];
        float phi = 0.f;
        #pragma unroll
        for (int t = 0; t < CHK; t++) {
            float f = __logf(g[t]); phi += f;
            E[t] = __expf(phi);
            U[t] = (1.f - g[t]) * __expf(-phi);
        }
    }
    float* okp = OK + gbase + tid;
    #pragma unroll
    for (int t = 0; t < CHK; t++) {
        float acc = 0.f;
        const int NG = (t < 32) ? 8 : 16;   // A is zero above the diagonal
        #pragma unroll
        for (int j = 0; j < NG; j++) {
            float4 a4 = *(const float4*)&Asc[t * 68 + j * 4];
            acc = fmaf(a4.x, U[4 * j + 0], acc);
            acc = fmaf(a4.y, U[4 * j + 1], acc);
            acc = fmaf(a4.z, U[4 * j + 2], acc);
            acc = fmaf(a4.w, U[4 * j + 3], acc);
        }
        okp[(size_t)t * 1024] = E[t] * (Gs[t * 260 + tid] + acc);
    }
}

// ---------------- softmax over M=256, in place ----------------
__global__ __launch_bounds__(256) void gsa_softmax(float* __restrict__ x) {
    int row = blockIdx.x * 4 + (threadIdx.x >> 6);
    int lane = threadIdx.x & 63;
    float* p = x + (size_t)row * 256 + lane * 4;
    float4 v = *(float4*)p;
    float mx = fmaxf(fmaxf(v.x, v.y), fmaxf(v.z, v.w));
    #pragma unroll
    for (int off = 32; off; off >>= 1) mx = fmaxf(mx, __shfl_xor(mx, off));
    v.x = expf(v.x - mx); v.y = expf(v.y - mx);
    v.z = expf(v.z - mx); v.w = expf(v.w - mx);
    float sm = v.x + v.y + v.z + v.w;
    #pragma unroll
    for (int off = 32; off; off >>= 1) sm += __shfl_xor(sm, off);
    float inv = 1.f / sm;
    v.x *= inv; v.y *= inv; v.z *= inv; v.w *= inv;
    *(float4*)p = v;
}

// ---------------- Phase C pass2: o = qe@S20^T + Bmask@V ----------------
// qe = qv*E ; B[t,tau] = sum_m qe[t,m]U[tau,m] (MFMA) ; P2 in fp32 VALU.
__global__ __launch_bounds__(256) void gsa_p2_out(const float* __restrict__ QV,
        const u16* __restrict__ Vb, const float* __restrict__ GKp,
        const u16* __restrict__ Sb, float* __restrict__ OV) {
    __shared__ u16 qe[64 * 264];
    __shared__ u16 Us[64 * 264];
    __shared__ float Bsc[64 * 68];
    __shared__ float Gs[64 * 260];
    int tid = threadIdx.x;
    int bh = blockIdx.x & 7, c = blockIdx.x >> 3;
    int b = bh >> 2, h = bh & 3, t0 = c * CHK;
    size_t gbase = ((size_t)(b * TLEN + t0)) * 1024 + h * 256;
    // scan per m=tid: write qe, U columns (conflict-free row writes per tau)
    {
        float g[CHK], qv[CHK];
        const float* gp = GKp + gbase + tid;
        const float* qp = QV + gbase + tid;
        #pragma unroll
        for (int t = 0; t < CHK; t++) g[t] = gp[(size_t)t * 1024];
        #pragma unroll
        for (int t = 0; t < CHK; t++) qv[t] = qp[(size_t)t * 1024];
        float phi = 0.f;
        #pragma unroll
        for (int t = 0; t < CHK; t++) {
            float f = __logf(g[t]); phi += f;
            float E = __expf(phi);
            qe[t * 264 + tid] = f2bf(qv[t] * E);
            Us[t * 264 + tid] = f2bf((1.f - g[t]) * __expf(-phi));
        }
    }
    __syncthreads();
    int w = tid >> 6, lane = tid & 63, frow = lane & 15, fq = lane >> 4;
    // G2 = qe @ S20 for v-range w*64 (S20[v][m] bf16 global B-op)
    {
        const u16* Sg = Sb + (size_t)(bh * NCHK + c) * 65536;
        f32x4 gac[4][4];
        #pragma unroll
        for (int tt = 0; tt < 4; tt++)
            #pragma unroll
            for (int vt = 0; vt < 4; vt++) gac[tt][vt] = (f32x4){0.f, 0.f, 0.f, 0.f};
        for (int ks = 0; ks < 8; ks++) {
            bf16x8 bfr[4], afr[4];
            #pragma unroll
            for (int vt = 0; vt < 4; vt++)
                bfr[vt] = *(const bf16x8*)(Sg + (size_t)(w * 64 + vt * 16 + frow) * 256 + ks * 32 + fq * 8);
            #pragma unroll
            for (int tt = 0; tt < 4; tt++)
                afr[tt] = *(const bf16x8*)&qe[(tt * 16 + frow) * 264 + ks * 32 + fq * 8];
            #pragma unroll
            for (int tt = 0; tt < 4; tt++)
                #pragma unroll
                for (int vt = 0; vt < 4; vt++)
                    gac[tt][vt] = MFMA(afr[tt], bfr[vt], gac[tt][vt]);
        }
        #pragma unroll
        for (int tt = 0; tt < 4; tt++)
            #pragma unroll
            for (int vt = 0; vt < 4; vt++)
                #pragma unroll
                for (int r = 0; r < 4; r++)
                    Gs[(tt * 16 + fq * 4 + r) * 260 + w * 64 + vt * 16 + frow] = gac[tt][vt][r];
    }
    // B = qe @ U^T for t-tile w, masked
    {
        #pragma unroll
        for (int tt = 0; tt < 4; tt++) {
            f32x4 ac = (f32x4){0.f, 0.f, 0.f, 0.f};
            #pragma unroll
            for (int ks = 0; ks < 8; ks++) {
                bf16x8 a = *(const bf16x8*)&qe[(w * 16 + frow) * 264 + ks * 32 + fq * 8];
                bf16x8 bb = *(const bf16x8*)&Us[(tt * 16 + frow) * 264 + ks * 32 + fq * 8];
                ac = MFMA(a, bb, ac);
            }
            #pragma unroll
            for (int r = 0; r < 4; r++) {
                int t = w * 16 + fq * 4 + r, tau = tt * 16 + frow;
                Bsc[t * 68 + tau] = (tau <= t) ? ac[r] : 0.f;
            }
        }
    }
    __syncthreads();
    // epilogue per v=tid: o = G2 + Bmask @ vcol
    float vcol[CHK];
    {
        const u16* vp = Vb + gbase + tid;
        #pragma unroll
        for (int t = 0; t < CHK; t++) vcol[t] = bf2f(vp[(size_t)t * 1024]);
    }
    float* ovp = OV + gbase + tid;
    #pragma unroll
    for (int t = 0; t < CHK; t++) {
        float acc = 0.f;
        const int NG = (t < 32) ? 8 : 16;
        #pragma unroll
        for (int j = 0; j < NG; j++) {
            float4 a4 = *(const float4*)&Bsc[t * 68 + j * 4];
            acc = fmaf(a4.x, vcol[4 * j + 0], acc);
            acc = fmaf(a4.y, vcol[4 * j + 1], acc);
            acc = fmaf(a4.z, vcol[4 * j + 2], acc);
            acc = fmaf(a4.w, vcol[4 * j + 3], acc);
        }
        ovp[(size_t)t * 1024] = Gs[t * 260 + tid] + acc;
    }
}

// ---------------- silu -> RMSNorm(1024) -> *g_w -> bf16 ----------------
__global__ __launch_bounds__(256) void gsa_rmsnorm(const float* __restrict__ ov,
        const void* __restrict__ gw, const int* __restrict__ flag,
        u16* __restrict__ out) {
    __shared__ float part[4];
    int row = blockIdx.x;
    int tid = threadIdx.x;
    const float* p = ov + (size_t)row * 1024 + tid * 4;
    float4 x = *(const float4*)p;
    float y0 = siluf(x.x), y1 = siluf(x.y), y2 = siluf(x.z), y3 = siluf(x.w);
    float ssum = y0 * y0 + y1 * y1 + y2 * y2 + y3 * y3;
    #pragma unroll
    for (int off = 32; off; off >>= 1) ssum += __shfl_xor(ssum, off);
    if ((tid & 63) == 0) part[tid >> 6] = ssum;
    __syncthreads();
    float tot = part[0] + part[1] + part[2] + part[3];
    float r = rsqrtf(tot * (1.f / 1024.f) + 1e-5f);
    float4 g;
    if (*flag) {
        ushort4 u = ((const ushort4*)gw)[tid];
        g.x = bf2f(u.x); g.y = bf2f(u.y); g.z = bf2f(u.z); g.w = bf2f(u.w);
    } else {
        g = ((const float4*)gw)[tid];
    }
    ushort4 o;
    o.x = f2bf(y0 * r * g.x); o.y = f2bf(y1 * r * g.y);
    o.z = f2bf(y2 * r * g.z); o.w = f2bf(y3 * r * g.w);
    ((ushort4*)(out + (size_t)row * 1024))[tid] = o;
}

// ---------------- launcher ----------------
extern "C" void kernel_launch(void* const* d_in, const int* in_sizes, int n_in,
                              void* d_out, int out_size, void* d_ws, size_t ws_size,
                              hipStream_t stream) {
    (void)in_sizes; (void)n_in; (void)out_size; (void)ws_size;
    const void* hs_raw = d_in[0];
    const void* wq_raw = d_in[1];
    const void* wk_raw = d_in[2];
    const void* wv_raw = d_in[3];
    const void* wf_raw = d_in[4];
    const void* gw_raw = d_in[5];
    const void* wo_raw = d_in[6];

    char* base = (char*)d_ws;
    int* flag = (int*)base;
    float* fb = (float*)(base + 256);
    const size_t F1M = 1048576;
    u16* Qb   = (u16*)fb;               // 8 MB bf16 [4096][1024]
    u16* Kb   = (u16*)(fb + 2 * F1M);   // 8 MB
    u16* Vb   = (u16*)(fb + 4 * F1M);   // 8 MB
    float* GK = fb + 6 * F1M;           // 16 MB fp32
    float* OK = fb + 10 * F1M;          // 16 MB fp32
    u16* Sbuf = (u16*)(fb + 14 * F1M);  // 33.5 MB: [8][32][256][256] bf16
    float* ECb = fb + 14 * F1M + 8388608;            // 65536 floats
    u16* Wb   = (u16*)(fb + 14 * F1M + 8388608 + 65536);  // 5 x 1M bf16 weights
    u16* WQb = Wb;
    u16* WKb = Wb + 1048576;
    u16* WVb = Wb + 2 * 1048576;
    u16* WFb = Wb + 3 * 1048576;
    u16* WOb = Wb + 4 * 1048576;
    u16* HSb  = (u16*)OK;   // staged bf16 hidden (dead after QKVF GEMM)
    float* OV = fb;         // over Qb/Kb (dead after p1_out/p2_out reads... Qb,Kb dead after p1_out; OV written by p2_out)
    u16* AN   = (u16*)OK;   // qv dead after p2_out
    float* FO = GK;         // GK dead after p2_out

    gsa_detect<<<1, 1, 0, stream>>>((const u32*)gw_raw, flag);
    gsa_tobf16<<<2048, 256, 0, stream>>>(hs_raw, HSb, 524288, flag);
    gsa_tobf16<<<512, 256, 0, stream>>>(wq_raw, WQb, 131072, flag);
    gsa_tobf16<<<512, 256, 0, stream>>>(wk_raw, WKb, 131072, flag);
    gsa_tobf16<<<512, 256, 0, stream>>>(wv_raw, WVb, 131072, flag);
    gsa_tobf16<<<512, 256, 0, stream>>>(wf_raw, WFb, 131072, flag);
    gsa_tobf16<<<512, 256, 0, stream>>>(wo_raw, WOb, 131072, flag);

    // fused QKVF: Q/K/V bf16 (silu), GK fp32 (gate); obfmask marks bf16 outs
    gsa_gemm_mfma<<<dim3(32, 32), 256, 0, stream>>>(HSb, WQb, WKb, WVb, WFb,
            Qb, Kb, Vb, GK, 0x01000000, 0x7);

    gsa_p_local<1><<<256, 256, 0, stream>>>(Kb, GK, Sbuf, ECb);
    gsa_scan1<<<512, 256, 0, stream>>>(Sbuf, ECb);
    gsa_p1_out<<<256, 256, 0, stream>>>(Qb, Kb, GK, Sbuf, OK);
    gsa_softmax<<<4096, 256, 0, stream>>>(OK);
    gsa_p_local<2><<<256, 256, 0, stream>>>(Vb, GK, Sbuf, ECb);
    gsa_scan2<<<512, 256, 0, stream>>>(Sbuf, ECb);
    gsa_p2_out<<<256, 256, 0, stream>>>(OK, Vb, GK, Sbuf, OV);

    gsa_rmsnorm<<<4096, 256, 0, stream>>>(OV, gw_raw, flag, AN);
    gsa_gemm_mfma<<<dim3(8, 32), 256, 0, stream>>>(AN, WOb, WOb, WOb, WOb,
            FO, FO, FO, FO, 0x02020202, 0x0);
    gsa_emit<<<4096, 256, 0, stream>>>(FO, d_out, 1048576, flag);
}